// Round 11
// baseline (462.176 us; speedup 1.0000x reference)
//
#include <hip/hip_runtime.h>
#include <stdint.h>

typedef unsigned long long u64;
typedef unsigned short ushort_t;
typedef __attribute__((ext_vector_type(8))) short short8;
typedef __attribute__((ext_vector_type(8))) _Float16 half8;
typedef __attribute__((ext_vector_type(16))) float f32x16;

// Dims: B=512,N=100 -> M=51200; T=100, L=50 conv pos, HE=64, E=128, NE=512, HD=256.

// ---------------- workspace layout (float offsets) ----------------
#define WS_ENCBHI   6656000ll    // 12288 ushort = 6144 f              -> end 6,662,144
#define WS_ENCBLO   6662144ll    // 6144 f                             -> end 6,668,288
#define WS_CBHI     6668288ll    // 65536 ushort = 32768 f             -> end 6,701,056
#define WS_CBLO     6701056ll    // 32768 f                            -> end 6,733,824
#define WS_CBNORM   6733824ll    // 512 f                              -> end 6,734,336
#define WS_D1F      6734336ll    // 32768 ushort = 16384 f             -> end 6,750,720
#define WS_D2F      6750720ll    // 65536 ushort = 32768 f             -> end 6,783,488
#define WS_D3F      6783488ll    // 32768 ushort = 16384 f             -> end 6,799,872
#define WS_ACCUMS   6799872ll    // 8 f32                              -> end 6,799,880
#define WS_RED      6902280ll    // red[51200*64] f32 = 3,276,800 f    -> end 10,179,080

__device__ __host__ inline ushort_t bf16_rn(float v) {
  unsigned u = __float_as_uint(v);
  unsigned r = (u + 0x7fffu + ((u >> 16) & 1u)) >> 16;
  return (ushort_t)r;
}
union h2u { _Float16 h; unsigned short u; };
union s2h { short8 s; half8 h; };

// packed RNE f32x2 -> bf16x2 (v_cvt_pk_bf16_f32); low 16 bits = a, high = b.
__device__ inline unsigned pk2_bf16(float a, float b) {
  unsigned r;
  asm("v_cvt_pk_bf16_f32 %0, %1, %2" : "=v"(r) : "v"(a), "v"(b));
  return r;
}

__device__ inline int rowfn(int r, int half) { return (r & 3) + 8*(r >> 2) + 4*half; }

#define MFMA_BF16 __builtin_amdgcn_mfma_f32_32x32x16_bf16
#define MFMA_F16  __builtin_amdgcn_mfma_f32_32x32x16_f16

// ---------------- prep: frag-pack all weights + codebook norms ----------------
__global__ __launch_bounds__(256) void prep_kernel(
    const float* __restrict__ w2, const float* __restrict__ cb,
    const float* __restrict__ d1w, const float* __restrict__ d2w,
    const float* __restrict__ d3w,
    ushort_t* __restrict__ ebhi, ushort_t* __restrict__ eblo,
    ushort_t* __restrict__ cbhi, ushort_t* __restrict__ cblo,
    ushort_t* __restrict__ d1f, ushort_t* __restrict__ d2f,
    ushort_t* __restrict__ d3f, float* __restrict__ cbnorm)
{
  const int total = 12288 + 65536 + 32768 + 65536 + 32768 + 512;
  for (int i = blockIdx.x*256 + threadIdx.x; i < total; i += gridDim.x*256) {
    int idx = i;
    if (idx < 12288) {
      // encoder conv2 B-frags (bf16 hi/lo), 32x32x16: f=((t*2+nt)*4+kt)
      int j = idx & 7, l6 = (idx >> 3) & 63, f = idx >> 9;
      int kt = f & 3, ntt = (f >> 2) & 1, t = f >> 3;
      int oc = ntt*32 + (l6 & 31);
      int ic = kt*16 + (l6 >> 5)*8 + j;
      float v = w2[(oc*64 + ic)*3 + t];
      ushort_t hi = bf16_rn(v);
      float hf = __uint_as_float(((unsigned)hi) << 16);
      ebhi[idx] = hi; eblo[idx] = bf16_rn(v - hf); continue;
    }
    idx -= 12288;
    if (idx < 65536) {
      // codebook f16 hi/lo frags, scaled x512: ntg16 x kt8
      int j = idx & 7, l6 = (idx >> 3) & 63, f = idx >> 9;
      int kt = f & 7, ntg = f >> 3;
      int k = kt*16 + (l6 >> 5)*8 + j;
      int n = ntg*32 + (l6 & 31);
      float v = cb[n*128 + k] * 512.0f;
      h2u a, b; a.h = (_Float16)v;
      b.h = (_Float16)(v - (float)a.h);
      cbhi[idx] = a.u; cblo[idx] = b.u; continue;
    }
    idx -= 65536;
    if (idx < 32768) {
      int j = idx & 7, l6 = (idx >> 3) & 63, f = idx >> 9;
      int kt = f & 7, ntg = f >> 3;
      int k = kt*16 + (l6 >> 5)*8 + j;
      int n = ntg*32 + (l6 & 31);
      d1f[idx] = bf16_rn(d1w[n*128 + k]); continue;
    }
    idx -= 32768;
    if (idx < 65536) {
      int j = idx & 7, l6 = (idx >> 3) & 63, f = idx >> 9;
      int kt = f & 15, ntg = f >> 4;
      int k = kt*16 + (l6 >> 5)*8 + j;
      int n = ntg*32 + (l6 & 31);
      d2f[idx] = bf16_rn(d2w[n*256 + k]); continue;
    }
    idx -= 65536;
    if (idx < 32768) {
      int j = idx & 7, l6 = (idx >> 3) & 63, f = idx >> 9;
      int kt = f & 15, ntg = f >> 4;
      int k = kt*16 + (l6 >> 5)*8 + j;
      int n = ntg*32 + (l6 & 31);
      d3f[idx] = (n < 100) ? bf16_rn(d3w[n*256 + k]) : (ushort_t)0; continue;
    }
    idx -= 32768;
    { double s = 0.0; const float* c = cb + idx*128;
      for (int e = 0; e < 128; ++e) { double v = (double)c[e]; s += v*v; }
      cbnorm[idx] = (float)s; }
  }
}

// ---------------- encoder v6: one wave per m, zero barriers, 3 blocks/CU ----------------
// Per-wave H slice: 52 rows x 256B (hi | lo planes), 16-slot XOR swizzle
// sw = ((row&7)<<4) | (((row>>3)&1)<<7). Zero halo rows 0/51 swizzle-invariant.
// LDS 53,248 B -> exactly 3 blocks/CU. No __syncthreads; intra-wave fence only.
__global__ __launch_bounds__(256, 3) void encoder_kernel(
    const float* __restrict__ x, const float* __restrict__ tm,
    const float* __restrict__ imask,
    const float* w1, const float* b1,
    const ushort_t* __restrict__ ebhi, const ushort_t* __restrict__ eblo,
    const float* b2, float* __restrict__ red)
{
  __shared__ ushort_t s_H[4][52*128];   // 53,248 B total
  const int tid  = threadIdx.x;
  const int wv   = __builtin_amdgcn_readfirstlane((int)(tid >> 6));
  const int lane = tid & 63;
  const int ln31 = lane & 31, half = lane >> 5;
  const long m   = (long)blockIdx.x*4 + wv;     // wave-uniform
  const float imv = imask[m];                   // scalar load
  ushort_t* Hw  = s_H[wv];

  // ---- conv1: inputs straight from global (3 float2 pairs per lane) ----
  {
    const int p = (lane < 50) ? lane : 0;
    const long xb = m*100 + 2*p;
    const float2 x0v = *(const float2*)(x + xb);
    const float2 t0v = *(const float2*)(tm + xb);
    float2 xmv = {0.f, 0.f}, tmv = {0.f, 0.f};
    float2 xpv = {0.f, 0.f}, tpv = {0.f, 0.f};
    if (p > 0)  { xmv = *(const float2*)(x + xb - 2); tmv = *(const float2*)(tm + xb - 2); }
    if (p < 49) { xpv = *(const float2*)(x + xb + 2); tpv = *(const float2*)(tm + xb + 2); }
    const float a0 = xmv.x*tmv.x, c0 = xmv.y*tmv.y;
    const float a1 = x0v.x*t0v.x, c1 = x0v.y*t0v.y;
    const float a2 = xpv.x*tpv.x, c2 = xpv.y*tpv.y;
    const int row = lane + 1;                    // H row = pos+1
    const int sw  = ((row & 7) << 4) | (((row >> 3) & 1) << 7);  // 16-slot swizzle
    char* rbase = (char*)(Hw + row*128);
    #pragma unroll
    for (int g = 0; g < 4; ++g) {
      unsigned hi8[8], lo8[8];
      #pragma unroll
      for (int pr = 0; pr < 8; ++pr) {
        const int o = g*16 + pr*2;
        const float* wA = w1 + (long)o*6;       // wave-uniform -> s_load
        const float* wB = wA + 6;
        float sA = 0.f, sB = 0.f;
        sA = fmaf(wA[0], a0, sA); sA = fmaf(wA[1], a1, sA); sA = fmaf(wA[2], a2, sA);
        sA = fmaf(wA[3], c0, sA); sA = fmaf(wA[4], c1, sA); sA = fmaf(wA[5], c2, sA);
        sB = fmaf(wB[0], a0, sB); sB = fmaf(wB[1], a1, sB); sB = fmaf(wB[2], a2, sB);
        sB = fmaf(wB[3], c0, sB); sB = fmaf(wB[4], c1, sB); sB = fmaf(wB[5], c2, sB);
        const float hA = fmaxf(fmaf(imv, sA, b1[o]),     0.f);
        const float hB = fmaxf(fmaf(imv, sB, b1[o + 1]), 0.f);
        const unsigned h = pk2_bf16(hA, hB);
        const float ha = __uint_as_float(h << 16);
        const float hb = __uint_as_float(h & 0xffff0000u);
        lo8[pr] = pk2_bf16(hA - ha, hB - hb);
        hi8[pr] = h;
      }
      if (lane < 50) {
        *(short8*)(rbase + ((g*32)        ^ sw)) = *(short8*)&hi8[0];
        *(short8*)(rbase + ((g*32 + 16)   ^ sw)) = *(short8*)&hi8[4];
        *(short8*)(rbase + ((g*32 + 128)  ^ sw)) = *(short8*)&lo8[0];
        *(short8*)(rbase + ((g*32 + 144)  ^ sw)) = *(short8*)&lo8[4];
      }
    }
    if (lane == 50 || lane == 51) {          // zero halo rows 0 and 51 (swizzle-invariant)
      const int zr = (lane == 50) ? 0 : 51;
      short8 z8 = {};
      short8* d = (short8*)(Hw + zr*128);
      #pragma unroll
      for (int i = 0; i < 16; ++i) d[i] = z8;
    }
  }
  // intra-wave LDS write->read fence (wave-private slice; no barrier)
  asm volatile("s_waitcnt lgkmcnt(0)" ::: "memory");
  __builtin_amdgcn_sched_barrier(0);

  // ---- conv2 MFMA: all 4 (mt,nt) tiles of this wave's m ----
  f32x16 acc00, acc01, acc10, acc11;
  #pragma unroll
  for (int q = 0; q < 16; ++q) { acc00[q] = 0.f; acc01[q] = 0.f; acc10[q] = 0.f; acc11[q] = 0.f; }
  {
    const short8* bh8 = (const short8*)ebhi;
    const short8* bl8 = (const short8*)eblo;
    for (int t = 0; t < 3; ++t) {
      const int r0 = ln31 + t;                // 0..33, valid
      int r1 = 32 + ln31 + t;                 // 32..65 -> clamp to zero halo 51
      if (r1 > 51) r1 = 51;
      const int sw0 = ((r0 & 7) << 4) | (((r0 >> 3) & 1) << 7);
      const int sw1 = ((r1 & 7) << 4) | (((r1 >> 3) & 1) << 7);
      const char* b0p = (const char*)(Hw + r0*128);
      const char* b1p = (const char*)(Hw + r1*128);
      #pragma unroll
      for (int kt = 0; kt < 4; ++kt) {
        const int f0 = (t*2 + 0)*4 + kt;
        const int f1 = (t*2 + 1)*4 + kt;
        const int offh = kt*32 + half*16;
        const short8 Bh0 = bh8[f0*64 + lane], Bl0 = bl8[f0*64 + lane];
        const short8 Bh1 = bh8[f1*64 + lane], Bl1 = bl8[f1*64 + lane];
        const short8 ah0 = *(const short8*)(b0p + (offh ^ sw0));
        const short8 al0 = *(const short8*)(b0p + ((offh + 128) ^ sw0));
        const short8 ah1 = *(const short8*)(b1p + (offh ^ sw1));
        const short8 al1 = *(const short8*)(b1p + ((offh + 128) ^ sw1));
        acc00 = MFMA_BF16(ah0, Bh0, acc00, 0, 0, 0);
        acc00 = MFMA_BF16(ah0, Bl0, acc00, 0, 0, 0);
        acc00 = MFMA_BF16(al0, Bh0, acc00, 0, 0, 0);
        acc01 = MFMA_BF16(ah0, Bh1, acc01, 0, 0, 0);
        acc01 = MFMA_BF16(ah0, Bl1, acc01, 0, 0, 0);
        acc01 = MFMA_BF16(al0, Bh1, acc01, 0, 0, 0);
        acc10 = MFMA_BF16(ah1, Bh0, acc10, 0, 0, 0);
        acc10 = MFMA_BF16(ah1, Bl0, acc10, 0, 0, 0);
        acc10 = MFMA_BF16(al1, Bh0, acc10, 0, 0, 0);
        acc11 = MFMA_BF16(ah1, Bh1, acc11, 0, 0, 0);
        acc11 = MFMA_BF16(ah1, Bl1, acc11, 0, 0, 0);
        acc11 = MFMA_BF16(al1, Bh1, acc11, 0, 0, 0);
      }
    }
  }

  // ---- relu + bias + masked position-sum -> red[m][64] (f32, global) ----
  {
    const float bv0 = b2[ln31];
    const float bv1 = b2[32 + ln31];
    float s0 = 0.f, s1 = 0.f;
    #pragma unroll
    for (int r = 0; r < 16; ++r) {
      s0 += fmaxf(acc00[r] + bv0, 0.f);              // mt=0: pos 0..31 all valid
      s1 += fmaxf(acc01[r] + bv1, 0.f);
      const int mpos = 32 + rowfn(r, half);          // mt=1: keep pos<50
      const float v10 = fmaxf(acc10[r] + bv0, 0.f);
      const float v11 = fmaxf(acc11[r] + bv1, 0.f);
      if (mpos < 50) { s0 += v10; s1 += v11; }
    }
    s0 += __shfl_xor(s0, 32);
    s1 += __shfl_xor(s1, 32);
    if (half == 0) {
      red[m*64 + ln31]      = s0;
      red[m*64 + 32 + ln31] = s1;
    }
  }
}

// ---------------- fused latent -> VQ -> decoder (64 m per block, R9 geometry) ----------------
// R10 lesson applied within the 64-m structure: VQ B-frags hoisted out of the
// mtl loop (halves VQ's fixed per-wave global-load volume); latent dot-product
// split into 4 accumulators (cuts dependent-FMA latency 4x). argmin set and
// per-(mtl,ct) accumulation order unchanged -> identical indices.
__global__ __launch_bounds__(256, 2) void vqdec_kernel(
    const float* __restrict__ red, const float* __restrict__ imask,
    const float* __restrict__ latw, const float* __restrict__ latb,
    const ushort_t* __restrict__ cbhi, const ushort_t* __restrict__ cblo,
    const float* __restrict__ cbnorm, const float* __restrict__ cb,
    const ushort_t* __restrict__ d1frag, const float* __restrict__ d1b,
    const ushort_t* __restrict__ d2frag, const float* __restrict__ d2b,
    const ushort_t* __restrict__ d3frag, const float* __restrict__ d3b,
    const float* __restrict__ x, const float* __restrict__ tm,
    float* __restrict__ xhat, float* __restrict__ out_idx,
    float* __restrict__ accums)
{
  __shared__ __attribute__((aligned(16))) ushort_t s_reg1[64*264];
  __shared__ __attribute__((aligned(16))) ushort_t s_reg2[64*264];
  __shared__ int s_idx[64];
  __shared__ float s_act[64];
  __shared__ float s_rn0[64], s_rn1[64];
  __shared__ u64 s_best[64];
  __shared__ float s_im[64];
  __shared__ float s_p[4], s_w[4];

  float*    s_r  = (float*)s_reg1;        // 4096 f32 (latent input)
  ushort_t* s_al = s_reg1 + 8192;         // 8704 ush (z lo frags), ends at 16896
  ushort_t* s_ah = s_reg2;                // 8704 ush (z hi frags)
  ushort_t* s_u  = s_reg1;                // gather A1 (stride 136) / h2 (stride 264)
  ushort_t* s_h1 = s_reg2;                // h1 (stride 264)

  const int tid = threadIdx.x;
  const long m0 = (long)blockIdx.x * 64;
  const int wv = tid >> 6, lane = tid & 63;
  const int ln31 = lane & 31, half = lane >> 5;

  // ---- stage: red -> s_r, imask -> s_im, init s_best ----
  {
    const int r = tid >> 2, seg = tid & 3;
    const float4* src = (const float4*)(red + (m0 + r)*64 + seg*16);
    float4* dst = (float4*)(s_r + r*64 + seg*16);
    dst[0] = src[0]; dst[1] = src[1]; dst[2] = src[2]; dst[3] = src[3];
  }
  if (tid < 64) { s_im[tid] = imask[m0 + tid]; s_best[tid] = ~0ULL; }
  __syncthreads();

  // ---- latent: z -> f16 hi/lo frags in LDS + rownorm partials ----
  {
    const int e = tid & 127, mh = tid >> 7;
    float4 W[16];
    const float4* wp = (const float4*)(latw + (long)e*64);
    #pragma unroll
    for (int q = 0; q < 16; ++q) W[q] = wp[q];
    const float lb = latb[e];
    for (int i = 0; i < 32; ++i) {
      const int ml = mh*32 + i;                        // wave-uniform
      const float4* rp = (const float4*)(s_r + ml*64); // LDS broadcast
      float a0 = 0.f, a1 = 0.f, a2 = 0.f, a3 = 0.f;    // 4 chains: latency/4
      #pragma unroll
      for (int q = 0; q < 16; q += 4) {
        const float4 r0 = rp[q],   r1 = rp[q+1];
        const float4 r2 = rp[q+2], r3 = rp[q+3];
        a0 = fmaf(W[q].x,   r0.x, a0); a0 = fmaf(W[q].y,   r0.y, a0);
        a0 = fmaf(W[q].z,   r0.z, a0); a0 = fmaf(W[q].w,   r0.w, a0);
        a1 = fmaf(W[q+1].x, r1.x, a1); a1 = fmaf(W[q+1].y, r1.y, a1);
        a1 = fmaf(W[q+1].z, r1.z, a1); a1 = fmaf(W[q+1].w, r1.w, a1);
        a2 = fmaf(W[q+2].x, r2.x, a2); a2 = fmaf(W[q+2].y, r2.y, a2);
        a2 = fmaf(W[q+2].z, r2.z, a2); a2 = fmaf(W[q+2].w, r2.w, a2);
        a3 = fmaf(W[q+3].x, r3.x, a3); a3 = fmaf(W[q+3].y, r3.y, a3);
        a3 = fmaf(W[q+3].z, r3.z, a3); a3 = fmaf(W[q+3].w, r3.w, a3);
      }
      const float a = (a0 + a1) + (a2 + a3);
      const float z = fmaf(0.02f, a, lb) * s_im[ml];
      h2u zh, zl; zh.h = (_Float16)z; zl.h = (_Float16)(z - (float)zh.h);
      s_ah[ml*136 + e] = zh.u;
      s_al[ml*136 + e] = zl.u;
      float v = z*z;
      #pragma unroll
      for (int off = 32; off > 0; off >>= 1) v += __shfl_down(v, off);
      if (lane == 0) { if (e < 64) s_rn0[ml] = v; else s_rn1[ml] = v; }
    }
  }
  __syncthreads();

  // ---- VQ: B-frags loaded once per ct, reused across both row-tiles ----
  {
    const short8* ch8 = (const short8*)cbhi;
    const short8* cl8 = (const short8*)cblo;
    float rnv[2][16];
    u64 best[2][16];
    #pragma unroll
    for (int mtl = 0; mtl < 2; ++mtl) {
      #pragma unroll
      for (int r = 0; r < 16; ++r) {
        const int g = mtl*32 + rowfn(r, half);
        rnv[mtl][r] = s_rn0[g] + s_rn1[g];
        best[mtl][r] = ~0ULL;
      }
    }
    for (int ct = 0; ct < 4; ++ct) {
      const int ntg = wv*4 + ct;
      half8 Bh[8], Bl[8];
      #pragma unroll
      for (int kt = 0; kt < 8; ++kt) {
        s2h a, b;
        a.s = ch8[(ntg*8 + kt)*64 + lane];
        b.s = cl8[(ntg*8 + kt)*64 + lane];
        Bh[kt] = a.h; Bl[kt] = b.h;
      }
      const int code = ntg*32 + ln31;
      const float nrm = cbnorm[code];
      #pragma unroll
      for (int mtl = 0; mtl < 2; ++mtl) {
        f32x16 acc;
        #pragma unroll
        for (int q = 0; q < 16; ++q) acc[q] = 0.f;
        const int base8 = (mtl*32 + ln31)*17 + half;
        #pragma unroll
        for (int kt = 0; kt < 8; ++kt) {
          s2h ah, al;
          ah.s = ((const short8*)s_ah)[base8 + kt*2];
          al.s = ((const short8*)s_al)[base8 + kt*2];
          acc = MFMA_F16(ah.h, Bh[kt], acc, 0, 0, 0);
          acc = MFMA_F16(ah.h, Bl[kt], acc, 0, 0, 0);
          acc = MFMA_F16(al.h, Bh[kt], acc, 0, 0, 0);
        }
        #pragma unroll
        for (int r = 0; r < 16; ++r) {
          const float t = fmaf(-0.00390625f, acc[r], rnv[mtl][r]);  // A - p/256 (cb x512)
          const float d = t + nrm;
          const u64 pk = ((u64)__float_as_uint(d) << 32) | (u64)(unsigned)code;
          if (pk < best[mtl][r]) best[mtl][r] = pk;
        }
      }
    }
    #pragma unroll
    for (int mtl = 0; mtl < 2; ++mtl) {
      #pragma unroll
      for (int r = 0; r < 16; ++r)
        atomicMin(&s_best[mtl*32 + rowfn(r, half)], best[mtl][r]);
    }
  }
  __syncthreads();

  // ---- P0: indices, vq-loss, S_im; gather zq*im -> s_u (stride 136) ----
  if (tid < 64) {
    const u64 pk = s_best[tid];
    const int ii = (int)(unsigned)(pk & 0xffffffffULL);
    const float dd = __uint_as_float((unsigned)(pk >> 32));
    const float imv = s_im[tid];
    s_idx[tid] = ii; s_act[tid] = imv;
    out_idx[m0 + tid] = (imv > 0.f) ? (float)ii : -1.0f;
    float vqp = 1.25f * dd * (1.0f/128.0f) * imv;
    float sim = imv;
    #pragma unroll
    for (int off = 32; off > 0; off >>= 1) {
      vqp += __shfl_down(vqp, off); sim += __shfl_down(sim, off);
    }
    if (tid == 0) { atomicAdd(&accums[1], vqp); atomicAdd(&accums[3], sim); }
  }
  __syncthreads();
  {
    const int row = tid >> 2, seg = tid & 3;
    const float4* src = (const float4*)(cb + (long)s_idx[row]*128 + seg*32);
    const float im = s_act[row];
    ushort_t tmp[32];
    #pragma unroll
    for (int q = 0; q < 8; ++q) {
      const float4 v = src[q];
      tmp[q*4+0] = bf16_rn(v.x*im); tmp[q*4+1] = bf16_rn(v.y*im);
      tmp[q*4+2] = bf16_rn(v.z*im); tmp[q*4+3] = bf16_rn(v.w*im);
    }
    short8* dst = (short8*)(s_u + row*136 + seg*32);
    #pragma unroll
    for (int q = 0; q < 4; ++q) dst[q] = *(short8*)&tmp[q*8];
  }
  __syncthreads();

  // ---- P1: GEMM1 (K=128): h1 = relu(zq @ d1^T + b) -> s_h1 (stride 264) ----
  {
    const short8* bf = (const short8*)d1frag;
    #pragma unroll
    for (int nti = 0; nti < 2; ++nti) {
      const int ntg = wv + nti*4;
      short8 B[8];
      #pragma unroll
      for (int kt = 0; kt < 8; ++kt) B[kt] = bf[(ntg*8 + kt)*64 + lane];
      const float bv = d1b[ntg*32 + ln31];
      #pragma unroll
      for (int mtl = 0; mtl < 2; ++mtl) {
        f32x16 acc;
        #pragma unroll
        for (int q = 0; q < 16; ++q) acc[q] = 0.f;
        const int base8 = (mtl*32 + ln31)*17 + half;
        #pragma unroll
        for (int kt = 0; kt < 8; ++kt) {
          const short8 a = ((const short8*)s_u)[base8 + kt*2];
          acc = MFMA_BF16(a, B[kt], acc, 0, 0, 0);
        }
        const int col = ntg*32 + ln31;
        #pragma unroll
        for (int r = 0; r < 16; ++r) {
          const int row = mtl*32 + rowfn(r, half);
          s_h1[row*264 + col] = bf16_rn(fmaxf(acc[r] + bv, 0.f));
        }
      }
    }
  }
  __syncthreads();

  // ---- P2: GEMM2 (K=256): h2 = relu(h1 @ d2^T + b) -> s_u (stride 264) ----
  {
    const short8* bf = (const short8*)d2frag;
    #pragma unroll
    for (int nti = 0; nti < 2; ++nti) {
      const int ntg = wv + nti*4;
      short8 B[16];
      #pragma unroll
      for (int kt = 0; kt < 16; ++kt) B[kt] = bf[(ntg*16 + kt)*64 + lane];
      const float bv = d2b[ntg*32 + ln31];
      #pragma unroll
      for (int mtl = 0; mtl < 2; ++mtl) {
        f32x16 acc;
        #pragma unroll
        for (int q = 0; q < 16; ++q) acc[q] = 0.f;
        const int base8 = (mtl*32 + ln31)*33 + half;
        #pragma unroll
        for (int kt = 0; kt < 16; ++kt) {
          const short8 a = ((const short8*)s_h1)[base8 + kt*2];
          acc = MFMA_BF16(a, B[kt], acc, 0, 0, 0);
        }
        const int col = ntg*32 + ln31;
        #pragma unroll
        for (int r = 0; r < 16; ++r) {
          const int row = mtl*32 + rowfn(r, half);
          s_u[row*264 + col] = bf16_rn(fmaxf(acc[r] + bv, 0.f));
        }
      }
    }
  }
  __syncthreads();

  // ---- P3: GEMM3 (K=256, N=100): x_hat + recon loss + S_rw ----
  {
    const short8* bf = (const short8*)d3frag;
    const int ntg = wv;
    short8 B[16];
    #pragma unroll
    for (int kt = 0; kt < 16; ++kt) B[kt] = bf[(ntg*16 + kt)*64 + lane];
    const int col = ntg*32 + ln31;
    const float bv = (col < 100) ? d3b[col] : 0.f;
    float part = 0.f, wsum = 0.f;
    #pragma unroll
    for (int mtl = 0; mtl < 2; ++mtl) {
      f32x16 acc;
      #pragma unroll
      for (int q = 0; q < 16; ++q) acc[q] = 0.f;
      const int base8 = (mtl*32 + ln31)*33 + half;
      #pragma unroll
      for (int kt = 0; kt < 16; ++kt) {
        const short8 a = ((const short8*)s_u)[base8 + kt*2];
        acc = MFMA_BF16(a, B[kt], acc, 0, 0, 0);
      }
      if (col < 100) {
        #pragma unroll
        for (int r = 0; r < 16; ++r) {
          const long row = m0 + mtl*32 + rowfn(r, half);
          const float xh = acc[r] + bv;
          xhat[row*100 + col] = xh;
          const float wgt = imask[row] * tm[row*100 + col];
          const float df = xh - x[row*100 + col];
          part = fmaf(df*df, wgt, part);
          wsum += wgt;
        }
      }
    }
    #pragma unroll
    for (int off = 32; off > 0; off >>= 1) {
      part += __shfl_down(part, off); wsum += __shfl_down(wsum, off);
    }
    if (lane == 0) { s_p[wv] = part; s_w[wv] = wsum; }
    __syncthreads();
    if (tid == 0) {
      atomicAdd(&accums[0], s_p[0]+s_p[1]+s_p[2]+s_p[3]);
      atomicAdd(&accums[2], s_w[0]+s_w[1]+s_w[2]+s_w[3]);
    }
  }
}

// ---------------- finalize scalars ----------------
__global__ void finalize_kernel(const float* __restrict__ accums, float* __restrict__ out) {
  if (threadIdx.x == 0 && blockIdx.x == 0) {
    out[5120000] = accums[0] / fmaxf(accums[2], 1.0f);
    out[5120001] = accums[1] / fmaxf(accums[3], 1.0f);
  }
}

extern "C" void kernel_launch(void* const* d_in, const int* in_sizes, int n_in,
                              void* d_out, int out_size, void* d_ws, size_t ws_size,
                              hipStream_t stream)
{
  (void)in_sizes; (void)n_in; (void)out_size; (void)ws_size;
  const float* x     = (const float*)d_in[0];
  const float* tmsk  = (const float*)d_in[1];
  const float* imask = (const float*)d_in[2];
  const float* w1    = (const float*)d_in[3];
  const float* b1    = (const float*)d_in[4];
  const float* w2    = (const float*)d_in[5];
  const float* b2    = (const float*)d_in[6];
  const float* latw  = (const float*)d_in[7];
  const float* latb  = (const float*)d_in[8];
  const float* cb    = (const float*)d_in[9];
  const float* d1w   = (const float*)d_in[10];
  const float* d1b   = (const float*)d_in[11];
  const float* d2w   = (const float*)d_in[12];
  const float* d2b   = (const float*)d_in[13];
  const float* d3w   = (const float*)d_in[14];
  const float* d3b   = (const float*)d_in[15];
  float* out = (float*)d_out;
  float* ws  = (float*)d_ws;

  ushort_t* ebhi   = (ushort_t*)(ws + WS_ENCBHI);
  ushort_t* eblo   = (ushort_t*)(ws + WS_ENCBLO);
  ushort_t* cbhi   = (ushort_t*)(ws + WS_CBHI);
  ushort_t* cblo   = (ushort_t*)(ws + WS_CBLO);
  float*    cbnorm = ws + WS_CBNORM;
  ushort_t* d1f    = (ushort_t*)(ws + WS_D1F);
  ushort_t* d2f    = (ushort_t*)(ws + WS_D2F);
  ushort_t* d3f    = (ushort_t*)(ws + WS_D3F);
  float*    accums = ws + WS_ACCUMS;
  float*    red    = ws + WS_RED;
  float* xhat    = out;
  float* out_idx = out + 5120002;

  hipMemsetAsync(accums, 0, 8*sizeof(float), stream);

  prep_kernel<<<512, 256, 0, stream>>>(w2, cb, d1w, d2w, d3w,
                                       ebhi, eblo, cbhi, cblo, d1f, d2f, d3f, cbnorm);
  encoder_kernel<<<12800, 256, 0, stream>>>(x, tmsk, imask, w1, b1, ebhi, eblo, b2, red);
  vqdec_kernel<<<800, 256, 0, stream>>>(red, imask, latw, latb, cbhi, cblo, cbnorm, cb,
                                        d1f, d1b, d2f, d2b, d3f, d3b, x, tmsk,
                                        xhat, out_idx, accums);
  finalize_kernel<<<1, 64, 0, stream>>>(accums, out);
}

// Round 12
// 424.805 us; speedup vs baseline: 1.0880x; 1.0880x over previous
//
#include <hip/hip_runtime.h>
#include <stdint.h>

typedef unsigned long long u64;
typedef unsigned short ushort_t;
typedef __attribute__((ext_vector_type(8))) short short8;
typedef __attribute__((ext_vector_type(8))) _Float16 half8;
typedef __attribute__((ext_vector_type(16))) float f32x16;

// Dims: B=512,N=100 -> M=51200; T=100, L=50 conv pos, HE=64, E=128, NE=512, HD=256.

// ---------------- workspace layout (float offsets) ----------------
#define WS_ENCBHI   6656000ll    // 12288 ushort = 6144 f              -> end 6,662,144
#define WS_ENCBLO   6662144ll    // 6144 f                             -> end 6,668,288
#define WS_CBHI     6668288ll    // 65536 ushort = 32768 f             -> end 6,701,056
#define WS_CBLO     6701056ll    // 32768 f                            -> end 6,733,824
#define WS_CBNORM   6733824ll    // 512 f                              -> end 6,734,336
#define WS_D1F      6734336ll    // 32768 ushort = 16384 f             -> end 6,750,720
#define WS_D2F      6750720ll    // 65536 ushort = 32768 f             -> end 6,783,488
#define WS_D3F      6783488ll    // 32768 ushort = 16384 f             -> end 6,799,872
#define WS_ACCUMS   6799872ll    // 8 f32                              -> end 6,799,880
#define WS_RED      6902280ll    // red[51200*64] f32 = 3,276,800 f    -> end 10,179,080

__device__ __host__ inline ushort_t bf16_rn(float v) {
  unsigned u = __float_as_uint(v);
  unsigned r = (u + 0x7fffu + ((u >> 16) & 1u)) >> 16;
  return (ushort_t)r;
}
union h2u { _Float16 h; unsigned short u; };
union s2h { short8 s; half8 h; };

// packed RNE f32x2 -> bf16x2 (v_cvt_pk_bf16_f32); low 16 bits = a, high = b.
__device__ inline unsigned pk2_bf16(float a, float b) {
  unsigned r;
  asm("v_cvt_pk_bf16_f32 %0, %1, %2" : "=v"(r) : "v"(a), "v"(b));
  return r;
}

__device__ inline int rowfn(int r, int half) { return (r & 3) + 8*(r >> 2) + 4*half; }

#define MFMA_BF16 __builtin_amdgcn_mfma_f32_32x32x16_bf16
#define MFMA_F16  __builtin_amdgcn_mfma_f32_32x32x16_f16

// ---------------- prep: frag-pack all weights + codebook norms ----------------
__global__ __launch_bounds__(256) void prep_kernel(
    const float* __restrict__ w2, const float* __restrict__ cb,
    const float* __restrict__ d1w, const float* __restrict__ d2w,
    const float* __restrict__ d3w,
    ushort_t* __restrict__ ebhi, ushort_t* __restrict__ eblo,
    ushort_t* __restrict__ cbhi, ushort_t* __restrict__ cblo,
    ushort_t* __restrict__ d1f, ushort_t* __restrict__ d2f,
    ushort_t* __restrict__ d3f, float* __restrict__ cbnorm)
{
  const int total = 12288 + 65536 + 32768 + 65536 + 32768 + 512;
  for (int i = blockIdx.x*256 + threadIdx.x; i < total; i += gridDim.x*256) {
    int idx = i;
    if (idx < 12288) {
      // encoder conv2 B-frags (bf16 hi/lo), 32x32x16: f=((t*2+nt)*4+kt)
      int j = idx & 7, l6 = (idx >> 3) & 63, f = idx >> 9;
      int kt = f & 3, ntt = (f >> 2) & 1, t = f >> 3;
      int oc = ntt*32 + (l6 & 31);
      int ic = kt*16 + (l6 >> 5)*8 + j;
      float v = w2[(oc*64 + ic)*3 + t];
      ushort_t hi = bf16_rn(v);
      float hf = __uint_as_float(((unsigned)hi) << 16);
      ebhi[idx] = hi; eblo[idx] = bf16_rn(v - hf); continue;
    }
    idx -= 12288;
    if (idx < 65536) {
      // codebook f16 hi/lo frags, scaled x512: ntg16 x kt8
      int j = idx & 7, l6 = (idx >> 3) & 63, f = idx >> 9;
      int kt = f & 7, ntg = f >> 3;
      int k = kt*16 + (l6 >> 5)*8 + j;
      int n = ntg*32 + (l6 & 31);
      float v = cb[n*128 + k] * 512.0f;
      h2u a, b; a.h = (_Float16)v;
      b.h = (_Float16)(v - (float)a.h);
      cbhi[idx] = a.u; cblo[idx] = b.u; continue;
    }
    idx -= 65536;
    if (idx < 32768) {
      int j = idx & 7, l6 = (idx >> 3) & 63, f = idx >> 9;
      int kt = f & 7, ntg = f >> 3;
      int k = kt*16 + (l6 >> 5)*8 + j;
      int n = ntg*32 + (l6 & 31);
      d1f[idx] = bf16_rn(d1w[n*128 + k]); continue;
    }
    idx -= 32768;
    if (idx < 65536) {
      int j = idx & 7, l6 = (idx >> 3) & 63, f = idx >> 9;
      int kt = f & 15, ntg = f >> 4;
      int k = kt*16 + (l6 >> 5)*8 + j;
      int n = ntg*32 + (l6 & 31);
      d2f[idx] = bf16_rn(d2w[n*256 + k]); continue;
    }
    idx -= 65536;
    if (idx < 32768) {
      int j = idx & 7, l6 = (idx >> 3) & 63, f = idx >> 9;
      int kt = f & 15, ntg = f >> 4;
      int k = kt*16 + (l6 >> 5)*8 + j;
      int n = ntg*32 + (l6 & 31);
      d3f[idx] = (n < 100) ? bf16_rn(d3w[n*256 + k]) : (ushort_t)0; continue;
    }
    idx -= 32768;
    { double s = 0.0; const float* c = cb + idx*128;
      for (int e = 0; e < 128; ++e) { double v = (double)c[e]; s += v*v; }
      cbnorm[idx] = (float)s; }
  }
}

// ---------------- encoder v6: one wave per m, zero barriers, 3 blocks/CU ----------------
// Per-wave H slice: 52 rows x 256B (hi | lo planes), 16-slot XOR swizzle
// sw = ((row&7)<<4) | (((row>>3)&1)<<7). Zero halo rows 0/51 swizzle-invariant.
// LDS 53,248 B -> exactly 3 blocks/CU. No __syncthreads; intra-wave fence only.
__global__ __launch_bounds__(256, 3) void encoder_kernel(
    const float* __restrict__ x, const float* __restrict__ tm,
    const float* __restrict__ imask,
    const float* w1, const float* b1,
    const ushort_t* __restrict__ ebhi, const ushort_t* __restrict__ eblo,
    const float* b2, float* __restrict__ red)
{
  __shared__ ushort_t s_H[4][52*128];   // 53,248 B total
  const int tid  = threadIdx.x;
  const int wv   = __builtin_amdgcn_readfirstlane((int)(tid >> 6));
  const int lane = tid & 63;
  const int ln31 = lane & 31, half = lane >> 5;
  const long m   = (long)blockIdx.x*4 + wv;     // wave-uniform
  const float imv = imask[m];                   // scalar load
  ushort_t* Hw  = s_H[wv];

  // ---- conv1: inputs straight from global (3 float2 pairs per lane) ----
  {
    const int p = (lane < 50) ? lane : 0;
    const long xb = m*100 + 2*p;
    const float2 x0v = *(const float2*)(x + xb);
    const float2 t0v = *(const float2*)(tm + xb);
    float2 xmv = {0.f, 0.f}, tmv = {0.f, 0.f};
    float2 xpv = {0.f, 0.f}, tpv = {0.f, 0.f};
    if (p > 0)  { xmv = *(const float2*)(x + xb - 2); tmv = *(const float2*)(tm + xb - 2); }
    if (p < 49) { xpv = *(const float2*)(x + xb + 2); tpv = *(const float2*)(tm + xb + 2); }
    const float a0 = xmv.x*tmv.x, c0 = xmv.y*tmv.y;
    const float a1 = x0v.x*t0v.x, c1 = x0v.y*t0v.y;
    const float a2 = xpv.x*tpv.x, c2 = xpv.y*tpv.y;
    const int row = lane + 1;                    // H row = pos+1
    const int sw  = ((row & 7) << 4) | (((row >> 3) & 1) << 7);  // 16-slot swizzle
    char* rbase = (char*)(Hw + row*128);
    #pragma unroll
    for (int g = 0; g < 4; ++g) {
      unsigned hi8[8], lo8[8];
      #pragma unroll
      for (int pr = 0; pr < 8; ++pr) {
        const int o = g*16 + pr*2;
        const float* wA = w1 + (long)o*6;       // wave-uniform -> s_load
        const float* wB = wA + 6;
        float sA = 0.f, sB = 0.f;
        sA = fmaf(wA[0], a0, sA); sA = fmaf(wA[1], a1, sA); sA = fmaf(wA[2], a2, sA);
        sA = fmaf(wA[3], c0, sA); sA = fmaf(wA[4], c1, sA); sA = fmaf(wA[5], c2, sA);
        sB = fmaf(wB[0], a0, sB); sB = fmaf(wB[1], a1, sB); sB = fmaf(wB[2], a2, sB);
        sB = fmaf(wB[3], c0, sB); sB = fmaf(wB[4], c1, sB); sB = fmaf(wB[5], c2, sB);
        const float hA = fmaxf(fmaf(imv, sA, b1[o]),     0.f);
        const float hB = fmaxf(fmaf(imv, sB, b1[o + 1]), 0.f);
        const unsigned h = pk2_bf16(hA, hB);
        const float ha = __uint_as_float(h << 16);
        const float hb = __uint_as_float(h & 0xffff0000u);
        lo8[pr] = pk2_bf16(hA - ha, hB - hb);
        hi8[pr] = h;
      }
      if (lane < 50) {
        *(short8*)(rbase + ((g*32)        ^ sw)) = *(short8*)&hi8[0];
        *(short8*)(rbase + ((g*32 + 16)   ^ sw)) = *(short8*)&hi8[4];
        *(short8*)(rbase + ((g*32 + 128)  ^ sw)) = *(short8*)&lo8[0];
        *(short8*)(rbase + ((g*32 + 144)  ^ sw)) = *(short8*)&lo8[4];
      }
    }
    if (lane == 50 || lane == 51) {          // zero halo rows 0 and 51 (swizzle-invariant)
      const int zr = (lane == 50) ? 0 : 51;
      short8 z8 = {};
      short8* d = (short8*)(Hw + zr*128);
      #pragma unroll
      for (int i = 0; i < 16; ++i) d[i] = z8;
    }
  }
  // intra-wave LDS write->read fence (wave-private slice; no barrier)
  asm volatile("s_waitcnt lgkmcnt(0)" ::: "memory");
  __builtin_amdgcn_sched_barrier(0);

  // ---- conv2 MFMA: all 4 (mt,nt) tiles of this wave's m ----
  f32x16 acc00, acc01, acc10, acc11;
  #pragma unroll
  for (int q = 0; q < 16; ++q) { acc00[q] = 0.f; acc01[q] = 0.f; acc10[q] = 0.f; acc11[q] = 0.f; }
  {
    const short8* bh8 = (const short8*)ebhi;
    const short8* bl8 = (const short8*)eblo;
    for (int t = 0; t < 3; ++t) {
      const int r0 = ln31 + t;                // 0..33, valid
      int r1 = 32 + ln31 + t;                 // 32..65 -> clamp to zero halo 51
      if (r1 > 51) r1 = 51;
      const int sw0 = ((r0 & 7) << 4) | (((r0 >> 3) & 1) << 7);
      const int sw1 = ((r1 & 7) << 4) | (((r1 >> 3) & 1) << 7);
      const char* b0p = (const char*)(Hw + r0*128);
      const char* b1p = (const char*)(Hw + r1*128);
      #pragma unroll
      for (int kt = 0; kt < 4; ++kt) {
        const int f0 = (t*2 + 0)*4 + kt;
        const int f1 = (t*2 + 1)*4 + kt;
        const int offh = kt*32 + half*16;
        const short8 Bh0 = bh8[f0*64 + lane], Bl0 = bl8[f0*64 + lane];
        const short8 Bh1 = bh8[f1*64 + lane], Bl1 = bl8[f1*64 + lane];
        const short8 ah0 = *(const short8*)(b0p + (offh ^ sw0));
        const short8 al0 = *(const short8*)(b0p + ((offh + 128) ^ sw0));
        const short8 ah1 = *(const short8*)(b1p + (offh ^ sw1));
        const short8 al1 = *(const short8*)(b1p + ((offh + 128) ^ sw1));
        acc00 = MFMA_BF16(ah0, Bh0, acc00, 0, 0, 0);
        acc00 = MFMA_BF16(ah0, Bl0, acc00, 0, 0, 0);
        acc00 = MFMA_BF16(al0, Bh0, acc00, 0, 0, 0);
        acc01 = MFMA_BF16(ah0, Bh1, acc01, 0, 0, 0);
        acc01 = MFMA_BF16(ah0, Bl1, acc01, 0, 0, 0);
        acc01 = MFMA_BF16(al0, Bh1, acc01, 0, 0, 0);
        acc10 = MFMA_BF16(ah1, Bh0, acc10, 0, 0, 0);
        acc10 = MFMA_BF16(ah1, Bl0, acc10, 0, 0, 0);
        acc10 = MFMA_BF16(al1, Bh0, acc10, 0, 0, 0);
        acc11 = MFMA_BF16(ah1, Bh1, acc11, 0, 0, 0);
        acc11 = MFMA_BF16(ah1, Bl1, acc11, 0, 0, 0);
        acc11 = MFMA_BF16(al1, Bh1, acc11, 0, 0, 0);
      }
    }
  }

  // ---- relu + bias + masked position-sum -> red[m][64] (f32, global) ----
  {
    const float bv0 = b2[ln31];
    const float bv1 = b2[32 + ln31];
    float s0 = 0.f, s1 = 0.f;
    #pragma unroll
    for (int r = 0; r < 16; ++r) {
      s0 += fmaxf(acc00[r] + bv0, 0.f);              // mt=0: pos 0..31 all valid
      s1 += fmaxf(acc01[r] + bv1, 0.f);
      const int mpos = 32 + rowfn(r, half);          // mt=1: keep pos<50
      const float v10 = fmaxf(acc10[r] + bv0, 0.f);
      const float v11 = fmaxf(acc11[r] + bv1, 0.f);
      if (mpos < 50) { s0 += v10; s1 += v11; }
    }
    s0 += __shfl_xor(s0, 32);
    s1 += __shfl_xor(s1, 32);
    if (half == 0) {
      red[m*64 + ln31]      = s0;
      red[m*64 + 32 + ln31] = s1;
    }
  }
}

// ---------------- fused latent -> VQ -> decoder (64 m per block, R9 champion) ----------------
// Exact R9 structure; ONLY change: latent dot-product uses 4 accumulator chains
// (validated in R11's passing run) to cut dependent-FMA latency 4x. VQ phase is
// R9's per-mtl form (no hoist -> no register-pressure spills).
__global__ __launch_bounds__(256, 2) void vqdec_kernel(
    const float* __restrict__ red, const float* __restrict__ imask,
    const float* __restrict__ latw, const float* __restrict__ latb,
    const ushort_t* __restrict__ cbhi, const ushort_t* __restrict__ cblo,
    const float* __restrict__ cbnorm, const float* __restrict__ cb,
    const ushort_t* __restrict__ d1frag, const float* __restrict__ d1b,
    const ushort_t* __restrict__ d2frag, const float* __restrict__ d2b,
    const ushort_t* __restrict__ d3frag, const float* __restrict__ d3b,
    const float* __restrict__ x, const float* __restrict__ tm,
    float* __restrict__ xhat, float* __restrict__ out_idx,
    float* __restrict__ accums)
{
  __shared__ __attribute__((aligned(16))) ushort_t s_reg1[64*264];
  __shared__ __attribute__((aligned(16))) ushort_t s_reg2[64*264];
  __shared__ int s_idx[64];
  __shared__ float s_act[64];
  __shared__ float s_rn0[64], s_rn1[64];
  __shared__ u64 s_best[64];
  __shared__ float s_im[64];
  __shared__ float s_p[4], s_w[4];

  float*    s_r  = (float*)s_reg1;        // 4096 f32 (latent input)
  ushort_t* s_al = s_reg1 + 8192;         // 8704 ush (z lo frags), ends at 16896
  ushort_t* s_ah = s_reg2;                // 8704 ush (z hi frags)
  ushort_t* s_u  = s_reg1;                // gather A1 (stride 136) / h2 (stride 264)
  ushort_t* s_h1 = s_reg2;                // h1 (stride 264)

  const int tid = threadIdx.x;
  const long m0 = (long)blockIdx.x * 64;
  const int wv = tid >> 6, lane = tid & 63;
  const int ln31 = lane & 31, half = lane >> 5;

  // ---- stage: red -> s_r, imask -> s_im, init s_best ----
  {
    const int r = tid >> 2, seg = tid & 3;
    const float4* src = (const float4*)(red + (m0 + r)*64 + seg*16);
    float4* dst = (float4*)(s_r + r*64 + seg*16);
    dst[0] = src[0]; dst[1] = src[1]; dst[2] = src[2]; dst[3] = src[3];
  }
  if (tid < 64) { s_im[tid] = imask[m0 + tid]; s_best[tid] = ~0ULL; }
  __syncthreads();

  // ---- latent: z -> f16 hi/lo frags in LDS + rownorm partials (4-chain FMA) ----
  {
    const int e = tid & 127, mh = tid >> 7;
    float4 W[16];
    const float4* wp = (const float4*)(latw + (long)e*64);
    #pragma unroll
    for (int q = 0; q < 16; ++q) W[q] = wp[q];
    const float lb = latb[e];
    for (int i = 0; i < 32; ++i) {
      const int ml = mh*32 + i;                        // wave-uniform
      const float4* rp = (const float4*)(s_r + ml*64); // LDS broadcast
      float a0 = 0.f, a1 = 0.f, a2 = 0.f, a3 = 0.f;    // 4 chains: latency/4
      #pragma unroll
      for (int q = 0; q < 16; q += 4) {
        const float4 r0 = rp[q],   r1 = rp[q+1];
        const float4 r2 = rp[q+2], r3 = rp[q+3];
        a0 = fmaf(W[q].x,   r0.x, a0); a0 = fmaf(W[q].y,   r0.y, a0);
        a0 = fmaf(W[q].z,   r0.z, a0); a0 = fmaf(W[q].w,   r0.w, a0);
        a1 = fmaf(W[q+1].x, r1.x, a1); a1 = fmaf(W[q+1].y, r1.y, a1);
        a1 = fmaf(W[q+1].z, r1.z, a1); a1 = fmaf(W[q+1].w, r1.w, a1);
        a2 = fmaf(W[q+2].x, r2.x, a2); a2 = fmaf(W[q+2].y, r2.y, a2);
        a2 = fmaf(W[q+2].z, r2.z, a2); a2 = fmaf(W[q+2].w, r2.w, a2);
        a3 = fmaf(W[q+3].x, r3.x, a3); a3 = fmaf(W[q+3].y, r3.y, a3);
        a3 = fmaf(W[q+3].z, r3.z, a3); a3 = fmaf(W[q+3].w, r3.w, a3);
      }
      const float a = (a0 + a1) + (a2 + a3);
      const float z = fmaf(0.02f, a, lb) * s_im[ml];
      h2u zh, zl; zh.h = (_Float16)z; zl.h = (_Float16)(z - (float)zh.h);
      s_ah[ml*136 + e] = zh.u;
      s_al[ml*136 + e] = zl.u;
      float v = z*z;
      #pragma unroll
      for (int off = 32; off > 0; off >>= 1) v += __shfl_down(v, off);
      if (lane == 0) { if (e < 64) s_rn0[ml] = v; else s_rn1[ml] = v; }
    }
  }
  __syncthreads();

  // ---- VQ: 2 row-tiles per wave x own 128 codes; argmin -> s_best (R9 form) ----
  {
    const short8* ch8 = (const short8*)cbhi;
    const short8* cl8 = (const short8*)cblo;
    #pragma unroll
    for (int mtl = 0; mtl < 2; ++mtl) {
      float rnv[16];
      #pragma unroll
      for (int r = 0; r < 16; ++r) {
        const int g = mtl*32 + rowfn(r, half);
        rnv[r] = s_rn0[g] + s_rn1[g];
      }
      u64 best[16];
      #pragma unroll
      for (int r = 0; r < 16; ++r) best[r] = ~0ULL;
      for (int ct = 0; ct < 4; ++ct) {
        const int ntg = wv*4 + ct;
        half8 Bh[8], Bl[8];
        #pragma unroll
        for (int kt = 0; kt < 8; ++kt) {
          s2h a, b;
          a.s = ch8[(ntg*8 + kt)*64 + lane];
          b.s = cl8[(ntg*8 + kt)*64 + lane];
          Bh[kt] = a.h; Bl[kt] = b.h;
        }
        f32x16 acc;
        #pragma unroll
        for (int q = 0; q < 16; ++q) acc[q] = 0.f;
        const int base8 = (mtl*32 + ln31)*17 + half;
        #pragma unroll
        for (int kt = 0; kt < 8; ++kt) {
          s2h ah, al;
          ah.s = ((const short8*)s_ah)[base8 + kt*2];
          al.s = ((const short8*)s_al)[base8 + kt*2];
          acc = MFMA_F16(ah.h, Bh[kt], acc, 0, 0, 0);
          acc = MFMA_F16(ah.h, Bl[kt], acc, 0, 0, 0);
          acc = MFMA_F16(al.h, Bh[kt], acc, 0, 0, 0);
        }
        const int code = ntg*32 + ln31;
        const float nrm = cbnorm[code];
        #pragma unroll
        for (int r = 0; r < 16; ++r) {
          const float t = fmaf(-0.00390625f, acc[r], rnv[r]);  // A - p/256 (cb x512)
          const float d = t + nrm;
          const u64 pk = ((u64)__float_as_uint(d) << 32) | (u64)(unsigned)code;
          if (pk < best[r]) best[r] = pk;
        }
      }
      #pragma unroll
      for (int r = 0; r < 16; ++r)
        atomicMin(&s_best[mtl*32 + rowfn(r, half)], best[r]);
    }
  }
  __syncthreads();

  // ---- P0: indices, vq-loss, S_im; gather zq*im -> s_u (stride 136) ----
  if (tid < 64) {
    const u64 pk = s_best[tid];
    const int ii = (int)(unsigned)(pk & 0xffffffffULL);
    const float dd = __uint_as_float((unsigned)(pk >> 32));
    const float imv = s_im[tid];
    s_idx[tid] = ii; s_act[tid] = imv;
    out_idx[m0 + tid] = (imv > 0.f) ? (float)ii : -1.0f;
    float vqp = 1.25f * dd * (1.0f/128.0f) * imv;
    float sim = imv;
    #pragma unroll
    for (int off = 32; off > 0; off >>= 1) {
      vqp += __shfl_down(vqp, off); sim += __shfl_down(sim, off);
    }
    if (tid == 0) { atomicAdd(&accums[1], vqp); atomicAdd(&accums[3], sim); }
  }
  __syncthreads();
  {
    const int row = tid >> 2, seg = tid & 3;
    const float4* src = (const float4*)(cb + (long)s_idx[row]*128 + seg*32);
    const float im = s_act[row];
    ushort_t tmp[32];
    #pragma unroll
    for (int q = 0; q < 8; ++q) {
      const float4 v = src[q];
      tmp[q*4+0] = bf16_rn(v.x*im); tmp[q*4+1] = bf16_rn(v.y*im);
      tmp[q*4+2] = bf16_rn(v.z*im); tmp[q*4+3] = bf16_rn(v.w*im);
    }
    short8* dst = (short8*)(s_u + row*136 + seg*32);
    #pragma unroll
    for (int q = 0; q < 4; ++q) dst[q] = *(short8*)&tmp[q*8];
  }
  __syncthreads();

  // ---- P1: GEMM1 (K=128): h1 = relu(zq @ d1^T + b) -> s_h1 (stride 264) ----
  {
    const short8* bf = (const short8*)d1frag;
    #pragma unroll
    for (int nti = 0; nti < 2; ++nti) {
      const int ntg = wv + nti*4;
      short8 B[8];
      #pragma unroll
      for (int kt = 0; kt < 8; ++kt) B[kt] = bf[(ntg*8 + kt)*64 + lane];
      const float bv = d1b[ntg*32 + ln31];
      #pragma unroll
      for (int mtl = 0; mtl < 2; ++mtl) {
        f32x16 acc;
        #pragma unroll
        for (int q = 0; q < 16; ++q) acc[q] = 0.f;
        const int base8 = (mtl*32 + ln31)*17 + half;
        #pragma unroll
        for (int kt = 0; kt < 8; ++kt) {
          const short8 a = ((const short8*)s_u)[base8 + kt*2];
          acc = MFMA_BF16(a, B[kt], acc, 0, 0, 0);
        }
        const int col = ntg*32 + ln31;
        #pragma unroll
        for (int r = 0; r < 16; ++r) {
          const int row = mtl*32 + rowfn(r, half);
          s_h1[row*264 + col] = bf16_rn(fmaxf(acc[r] + bv, 0.f));
        }
      }
    }
  }
  __syncthreads();

  // ---- P2: GEMM2 (K=256): h2 = relu(h1 @ d2^T + b) -> s_u (stride 264) ----
  {
    const short8* bf = (const short8*)d2frag;
    #pragma unroll
    for (int nti = 0; nti < 2; ++nti) {
      const int ntg = wv + nti*4;
      short8 B[16];
      #pragma unroll
      for (int kt = 0; kt < 16; ++kt) B[kt] = bf[(ntg*16 + kt)*64 + lane];
      const float bv = d2b[ntg*32 + ln31];
      #pragma unroll
      for (int mtl = 0; mtl < 2; ++mtl) {
        f32x16 acc;
        #pragma unroll
        for (int q = 0; q < 16; ++q) acc[q] = 0.f;
        const int base8 = (mtl*32 + ln31)*33 + half;
        #pragma unroll
        for (int kt = 0; kt < 16; ++kt) {
          const short8 a = ((const short8*)s_h1)[base8 + kt*2];
          acc = MFMA_BF16(a, B[kt], acc, 0, 0, 0);
        }
        const int col = ntg*32 + ln31;
        #pragma unroll
        for (int r = 0; r < 16; ++r) {
          const int row = mtl*32 + rowfn(r, half);
          s_u[row*264 + col] = bf16_rn(fmaxf(acc[r] + bv, 0.f));
        }
      }
    }
  }
  __syncthreads();

  // ---- P3: GEMM3 (K=256, N=100): x_hat + recon loss + S_rw ----
  {
    const short8* bf = (const short8*)d3frag;
    const int ntg = wv;
    short8 B[16];
    #pragma unroll
    for (int kt = 0; kt < 16; ++kt) B[kt] = bf[(ntg*16 + kt)*64 + lane];
    const int col = ntg*32 + ln31;
    const float bv = (col < 100) ? d3b[col] : 0.f;
    float part = 0.f, wsum = 0.f;
    #pragma unroll
    for (int mtl = 0; mtl < 2; ++mtl) {
      f32x16 acc;
      #pragma unroll
      for (int q = 0; q < 16; ++q) acc[q] = 0.f;
      const int base8 = (mtl*32 + ln31)*33 + half;
      #pragma unroll
      for (int kt = 0; kt < 16; ++kt) {
        const short8 a = ((const short8*)s_u)[base8 + kt*2];
        acc = MFMA_BF16(a, B[kt], acc, 0, 0, 0);
      }
      if (col < 100) {
        #pragma unroll
        for (int r = 0; r < 16; ++r) {
          const long row = m0 + mtl*32 + rowfn(r, half);
          const float xh = acc[r] + bv;
          xhat[row*100 + col] = xh;
          const float wgt = imask[row] * tm[row*100 + col];
          const float df = xh - x[row*100 + col];
          part = fmaf(df*df, wgt, part);
          wsum += wgt;
        }
      }
    }
    #pragma unroll
    for (int off = 32; off > 0; off >>= 1) {
      part += __shfl_down(part, off); wsum += __shfl_down(wsum, off);
    }
    if (lane == 0) { s_p[wv] = part; s_w[wv] = wsum; }
    __syncthreads();
    if (tid == 0) {
      atomicAdd(&accums[0], s_p[0]+s_p[1]+s_p[2]+s_p[3]);
      atomicAdd(&accums[2], s_w[0]+s_w[1]+s_w[2]+s_w[3]);
    }
  }
}

// ---------------- finalize scalars ----------------
__global__ void finalize_kernel(const float* __restrict__ accums, float* __restrict__ out) {
  if (threadIdx.x == 0 && blockIdx.x == 0) {
    out[5120000] = accums[0] / fmaxf(accums[2], 1.0f);
    out[5120001] = accums[1] / fmaxf(accums[3], 1.0f);
  }
}

extern "C" void kernel_launch(void* const* d_in, const int* in_sizes, int n_in,
                              void* d_out, int out_size, void* d_ws, size_t ws_size,
                              hipStream_t stream)
{
  (void)in_sizes; (void)n_in; (void)out_size; (void)ws_size;
  const float* x     = (const float*)d_in[0];
  const float* tmsk  = (const float*)d_in[1];
  const float* imask = (const float*)d_in[2];
  const float* w1    = (const float*)d_in[3];
  const float* b1    = (const float*)d_in[4];
  const float* w2    = (const float*)d_in[5];
  const float* b2    = (const float*)d_in[6];
  const float* latw  = (const float*)d_in[7];
  const float* latb  = (const float*)d_in[8];
  const float* cb    = (const float*)d_in[9];
  const float* d1w   = (const float*)d_in[10];
  const float* d1b   = (const float*)d_in[11];
  const float* d2w   = (const float*)d_in[12];
  const float* d2b   = (const float*)d_in[13];
  const float* d3w   = (const float*)d_in[14];
  const float* d3b   = (const float*)d_in[15];
  float* out = (float*)d_out;
  float* ws  = (float*)d_ws;

  ushort_t* ebhi   = (ushort_t*)(ws + WS_ENCBHI);
  ushort_t* eblo   = (ushort_t*)(ws + WS_ENCBLO);
  ushort_t* cbhi   = (ushort_t*)(ws + WS_CBHI);
  ushort_t* cblo   = (ushort_t*)(ws + WS_CBLO);
  float*    cbnorm = ws + WS_CBNORM;
  ushort_t* d1f    = (ushort_t*)(ws + WS_D1F);
  ushort_t* d2f    = (ushort_t*)(ws + WS_D2F);
  ushort_t* d3f    = (ushort_t*)(ws + WS_D3F);
  float*    accums = ws + WS_ACCUMS;
  float*    red    = ws + WS_RED;
  float* xhat    = out;
  float* out_idx = out + 5120002;

  hipMemsetAsync(accums, 0, 8*sizeof(float), stream);

  prep_kernel<<<512, 256, 0, stream>>>(w2, cb, d1w, d2w, d3w,
                                       ebhi, eblo, cbhi, cblo, d1f, d2f, d3f, cbnorm);
  encoder_kernel<<<12800, 256, 0, stream>>>(x, tmsk, imask, w1, b1, ebhi, eblo, b2, red);
  vqdec_kernel<<<800, 256, 0, stream>>>(red, imask, latw, latb, cbhi, cblo, cbnorm, cb,
                                        d1f, d1b, d2f, d2b, d3f, d3b, x, tmsk,
                                        xhat, out_idx, accums);
  finalize_kernel<<<1, 64, 0, stream>>>(accums, out);
}

// Round 14
// 423.499 us; speedup vs baseline: 1.0913x; 1.0031x over previous
//
#include <hip/hip_runtime.h>
#include <stdint.h>

typedef unsigned long long u64;
typedef unsigned short ushort_t;
typedef __attribute__((ext_vector_type(8))) short short8;
typedef __attribute__((ext_vector_type(8))) _Float16 half8;
typedef __attribute__((ext_vector_type(16))) float f32x16;

// Dims: B=512,N=100 -> M=51200; T=100, L=50 conv pos, HE=64, E=128, NE=512, HD=256.
#define VQDEC_BLOCKS 800

// ---------------- workspace layout (float offsets) ----------------
#define WS_ENCBHI   6656000ll    // 12288 ushort = 6144 f              -> end 6,662,144
#define WS_ENCBLO   6662144ll    // 6144 f                             -> end 6,668,288
#define WS_CBHI     6668288ll    // 65536 ushort = 32768 f             -> end 6,701,056
#define WS_CBLO     6701056ll    // 32768 f                            -> end 6,733,824
#define WS_CBNORM   6733824ll    // 512 f                              -> end 6,734,336
#define WS_D1F      6734336ll    // 32768 ushort = 16384 f             -> end 6,750,720
#define WS_D2F      6750720ll    // 65536 ushort = 32768 f             -> end 6,783,488
#define WS_D3F      6783488ll    // 32768 ushort = 16384 f             -> end 6,799,872
#define WS_RED      6902280ll    // red[51200*64] f32 = 3,276,800 f    -> end 10,179,080
#define WS_PART     10179080ll   // 800 blocks x 4 f32 partials        -> end 10,182,280

__device__ __host__ inline ushort_t bf16_rn(float v) {
  unsigned u = __float_as_uint(v);
  unsigned r = (u + 0x7fffu + ((u >> 16) & 1u)) >> 16;
  return (ushort_t)r;
}
union h2u { _Float16 h; unsigned short u; };
union s2h { short8 s; half8 h; };

// packed RNE f32x2 -> bf16x2 (v_cvt_pk_bf16_f32); low 16 bits = a, high = b.
__device__ inline unsigned pk2_bf16(float a, float b) {
  unsigned r;
  asm("v_cvt_pk_bf16_f32 %0, %1, %2" : "=v"(r) : "v"(a), "v"(b));
  return r;
}

__device__ inline int rowfn(int r, int half) { return (r & 3) + 8*(r >> 2) + 4*half; }

#define MFMA_BF16 __builtin_amdgcn_mfma_f32_32x32x16_bf16
#define MFMA_F16  __builtin_amdgcn_mfma_f32_32x32x16_f16

// ---------------- prep: frag-pack all weights + codebook norms ----------------
__global__ __launch_bounds__(256) void prep_kernel(
    const float* __restrict__ w2, const float* __restrict__ cb,
    const float* __restrict__ d1w, const float* __restrict__ d2w,
    const float* __restrict__ d3w,
    ushort_t* __restrict__ ebhi, ushort_t* __restrict__ eblo,
    ushort_t* __restrict__ cbhi, ushort_t* __restrict__ cblo,
    ushort_t* __restrict__ d1f, ushort_t* __restrict__ d2f,
    ushort_t* __restrict__ d3f, float* __restrict__ cbnorm)
{
  const int total = 12288 + 65536 + 32768 + 65536 + 32768 + 512;
  for (int i = blockIdx.x*256 + threadIdx.x; i < total; i += gridDim.x*256) {
    int idx = i;
    if (idx < 12288) {
      // encoder conv2 B-frags (bf16 hi/lo), 32x32x16: f=((t*2+nt)*4+kt)
      int j = idx & 7, l6 = (idx >> 3) & 63, f = idx >> 9;
      int kt = f & 3, ntt = (f >> 2) & 1, t = f >> 3;
      int oc = ntt*32 + (l6 & 31);
      int ic = kt*16 + (l6 >> 5)*8 + j;
      float v = w2[(oc*64 + ic)*3 + t];
      ushort_t hi = bf16_rn(v);
      float hf = __uint_as_float(((unsigned)hi) << 16);
      ebhi[idx] = hi; eblo[idx] = bf16_rn(v - hf); continue;
    }
    idx -= 12288;
    if (idx < 65536) {
      // codebook f16 hi/lo frags, scaled x512: ntg16 x kt8
      int j = idx & 7, l6 = (idx >> 3) & 63, f = idx >> 9;
      int kt = f & 7, ntg = f >> 3;
      int k = kt*16 + (l6 >> 5)*8 + j;
      int n = ntg*32 + (l6 & 31);
      float v = cb[n*128 + k] * 512.0f;
      h2u a, b; a.h = (_Float16)v;
      b.h = (_Float16)(v - (float)a.h);
      cbhi[idx] = a.u; cblo[idx] = b.u; continue;
    }
    idx -= 65536;
    if (idx < 32768) {
      int j = idx & 7, l6 = (idx >> 3) & 63, f = idx >> 9;
      int kt = f & 7, ntg = f >> 3;
      int k = kt*16 + (l6 >> 5)*8 + j;
      int n = ntg*32 + (l6 & 31);
      d1f[idx] = bf16_rn(d1w[n*128 + k]); continue;
    }
    idx -= 32768;
    if (idx < 65536) {
      int j = idx & 7, l6 = (idx >> 3) & 63, f = idx >> 9;
      int kt = f & 15, ntg = f >> 4;
      int k = kt*16 + (l6 >> 5)*8 + j;
      int n = ntg*32 + (l6 & 31);
      d2f[idx] = bf16_rn(d2w[n*256 + k]); continue;
    }
    idx -= 65536;
    if (idx < 32768) {
      int j = idx & 7, l6 = (idx >> 3) & 63, f = idx >> 9;
      int kt = f & 15, ntg = f >> 4;
      int k = kt*16 + (l6 >> 5)*8 + j;
      int n = ntg*32 + (l6 & 31);
      d3f[idx] = (n < 100) ? bf16_rn(d3w[n*256 + k]) : (ushort_t)0; continue;
    }
    idx -= 32768;
    { double s = 0.0; const float* c = cb + idx*128;
      for (int e = 0; e < 128; ++e) { double v = (double)c[e]; s += v*v; }
      cbnorm[idx] = (float)s; }
  }
}

// ---------------- encoder v6: one wave per m, zero barriers, 3 blocks/CU ----------------
// Per-wave H slice: 52 rows x 256B (hi | lo planes), 16-slot XOR swizzle
// sw = ((row&7)<<4) | (((row>>3)&1)<<7). Zero halo rows 0/51 swizzle-invariant.
// LDS 53,248 B -> exactly 3 blocks/CU. No __syncthreads; intra-wave fence only.
__global__ __launch_bounds__(256, 3) void encoder_kernel(
    const float* __restrict__ x, const float* __restrict__ tm,
    const float* __restrict__ imask,
    const float* w1, const float* b1,
    const ushort_t* __restrict__ ebhi, const ushort_t* __restrict__ eblo,
    const float* b2, float* __restrict__ red)
{
  __shared__ ushort_t s_H[4][52*128];   // 53,248 B total
  const int tid  = threadIdx.x;
  const int wv   = __builtin_amdgcn_readfirstlane((int)(tid >> 6));
  const int lane = tid & 63;
  const int ln31 = lane & 31, half = lane >> 5;
  const long m   = (long)blockIdx.x*4 + wv;     // wave-uniform
  const float imv = imask[m];                   // scalar load
  ushort_t* Hw  = s_H[wv];

  // ---- conv1: inputs straight from global (3 float2 pairs per lane) ----
  {
    const int p = (lane < 50) ? lane : 0;
    const long xb = m*100 + 2*p;
    const float2 x0v = *(const float2*)(x + xb);
    const float2 t0v = *(const float2*)(tm + xb);
    float2 xmv = {0.f, 0.f}, tmv = {0.f, 0.f};
    float2 xpv = {0.f, 0.f}, tpv = {0.f, 0.f};
    if (p > 0)  { xmv = *(const float2*)(x + xb - 2); tmv = *(const float2*)(tm + xb - 2); }
    if (p < 49) { xpv = *(const float2*)(x + xb + 2); tpv = *(const float2*)(tm + xb + 2); }
    const float a0 = xmv.x*tmv.x, c0 = xmv.y*tmv.y;
    const float a1 = x0v.x*t0v.x, c1 = x0v.y*t0v.y;
    const float a2 = xpv.x*tpv.x, c2 = xpv.y*tpv.y;
    const int row = lane + 1;                    // H row = pos+1
    const int sw  = ((row & 7) << 4) | (((row >> 3) & 1) << 7);  // 16-slot swizzle
    char* rbase = (char*)(Hw + row*128);
    #pragma unroll
    for (int g = 0; g < 4; ++g) {
      unsigned hi8[8], lo8[8];
      #pragma unroll
      for (int pr = 0; pr < 8; ++pr) {
        const int o = g*16 + pr*2;
        const float* wA = w1 + (long)o*6;       // wave-uniform -> s_load
        const float* wB = wA + 6;
        float sA = 0.f, sB = 0.f;
        sA = fmaf(wA[0], a0, sA); sA = fmaf(wA[1], a1, sA); sA = fmaf(wA[2], a2, sA);
        sA = fmaf(wA[3], c0, sA); sA = fmaf(wA[4], c1, sA); sA = fmaf(wA[5], c2, sA);
        sB = fmaf(wB[0], a0, sB); sB = fmaf(wB[1], a1, sB); sB = fmaf(wB[2], a2, sB);
        sB = fmaf(wB[3], c0, sB); sB = fmaf(wB[4], c1, sB); sB = fmaf(wB[5], c2, sB);
        const float hA = fmaxf(fmaf(imv, sA, b1[o]),     0.f);
        const float hB = fmaxf(fmaf(imv, sB, b1[o + 1]), 0.f);
        const unsigned h = pk2_bf16(hA, hB);
        const float ha = __uint_as_float(h << 16);
        const float hb = __uint_as_float(h & 0xffff0000u);
        lo8[pr] = pk2_bf16(hA - ha, hB - hb);
        hi8[pr] = h;
      }
      if (lane < 50) {
        *(short8*)(rbase + ((g*32)        ^ sw)) = *(short8*)&hi8[0];
        *(short8*)(rbase + ((g*32 + 16)   ^ sw)) = *(short8*)&hi8[4];
        *(short8*)(rbase + ((g*32 + 128)  ^ sw)) = *(short8*)&lo8[0];
        *(short8*)(rbase + ((g*32 + 144)  ^ sw)) = *(short8*)&lo8[4];
      }
    }
    if (lane == 50 || lane == 51) {          // zero halo rows 0 and 51 (swizzle-invariant)
      const int zr = (lane == 50) ? 0 : 51;
      short8 z8 = {};
      short8* d = (short8*)(Hw + zr*128);
      #pragma unroll
      for (int i = 0; i < 16; ++i) d[i] = z8;
    }
  }
  // intra-wave LDS write->read fence (wave-private slice; no barrier)
  asm volatile("s_waitcnt lgkmcnt(0)" ::: "memory");
  __builtin_amdgcn_sched_barrier(0);

  // ---- conv2 MFMA: all 4 (mt,nt) tiles of this wave's m ----
  f32x16 acc00, acc01, acc10, acc11;
  #pragma unroll
  for (int q = 0; q < 16; ++q) { acc00[q] = 0.f; acc01[q] = 0.f; acc10[q] = 0.f; acc11[q] = 0.f; }
  {
    const short8* bh8 = (const short8*)ebhi;
    const short8* bl8 = (const short8*)eblo;
    for (int t = 0; t < 3; ++t) {
      const int r0 = ln31 + t;                // 0..33, valid
      int r1 = 32 + ln31 + t;                 // 32..65 -> clamp to zero halo 51
      if (r1 > 51) r1 = 51;
      const int sw0 = ((r0 & 7) << 4) | (((r0 >> 3) & 1) << 7);
      const int sw1 = ((r1 & 7) << 4) | (((r1 >> 3) & 1) << 7);
      const char* b0p = (const char*)(Hw + r0*128);
      const char* b1p = (const char*)(Hw + r1*128);
      #pragma unroll
      for (int kt = 0; kt < 4; ++kt) {
        const int f0 = (t*2 + 0)*4 + kt;
        const int f1 = (t*2 + 1)*4 + kt;
        const int offh = kt*32 + half*16;
        const short8 Bh0 = bh8[f0*64 + lane], Bl0 = bl8[f0*64 + lane];
        const short8 Bh1 = bh8[f1*64 + lane], Bl1 = bl8[f1*64 + lane];
        const short8 ah0 = *(const short8*)(b0p + (offh ^ sw0));
        const short8 al0 = *(const short8*)(b0p + ((offh + 128) ^ sw0));
        const short8 ah1 = *(const short8*)(b1p + (offh ^ sw1));
        const short8 al1 = *(const short8*)(b1p + ((offh + 128) ^ sw1));
        acc00 = MFMA_BF16(ah0, Bh0, acc00, 0, 0, 0);
        acc00 = MFMA_BF16(ah0, Bl0, acc00, 0, 0, 0);
        acc00 = MFMA_BF16(al0, Bh0, acc00, 0, 0, 0);
        acc01 = MFMA_BF16(ah0, Bh1, acc01, 0, 0, 0);
        acc01 = MFMA_BF16(ah0, Bl1, acc01, 0, 0, 0);
        acc01 = MFMA_BF16(al0, Bh1, acc01, 0, 0, 0);
        acc10 = MFMA_BF16(ah1, Bh0, acc10, 0, 0, 0);
        acc10 = MFMA_BF16(ah1, Bl0, acc10, 0, 0, 0);
        acc10 = MFMA_BF16(al1, Bh0, acc10, 0, 0, 0);
        acc11 = MFMA_BF16(ah1, Bh1, acc11, 0, 0, 0);
        acc11 = MFMA_BF16(ah1, Bl1, acc11, 0, 0, 0);
        acc11 = MFMA_BF16(al1, Bh1, acc11, 0, 0, 0);
      }
    }
  }

  // ---- relu + bias + masked position-sum -> red[m][64] (f32, global) ----
  {
    const float bv0 = b2[ln31];
    const float bv1 = b2[32 + ln31];
    float s0 = 0.f, s1 = 0.f;
    #pragma unroll
    for (int r = 0; r < 16; ++r) {
      s0 += fmaxf(acc00[r] + bv0, 0.f);              // mt=0: pos 0..31 all valid
      s1 += fmaxf(acc01[r] + bv1, 0.f);
      const int mpos = 32 + rowfn(r, half);          // mt=1: keep pos<50
      const float v10 = fmaxf(acc10[r] + bv0, 0.f);
      const float v11 = fmaxf(acc11[r] + bv1, 0.f);
      if (mpos < 50) { s0 += v10; s1 += v11; }
    }
    s0 += __shfl_xor(s0, 32);
    s1 += __shfl_xor(s1, 32);
    if (half == 0) {
      red[m*64 + ln31]      = s0;
      red[m*64 + 32 + ln31] = s1;
    }
  }
}

// ---------------- fused latent -> VQ -> decoder (64 m per block, R12 champion) ----------------
// ONLY change vs R12: global atomics to accums (one cache line, ~4800 serialized
// cross-XCD RMWs) replaced by per-block plain-store partials (pblk[b*4+0..3]);
// finalize reduces. Guideline 12: per-block partials first, no contended atomics.
__global__ __launch_bounds__(256, 2) void vqdec_kernel(
    const float* __restrict__ red, const float* __restrict__ imask,
    const float* __restrict__ latw, const float* __restrict__ latb,
    const ushort_t* __restrict__ cbhi, const ushort_t* __restrict__ cblo,
    const float* __restrict__ cbnorm, const float* __restrict__ cb,
    const ushort_t* __restrict__ d1frag, const float* __restrict__ d1b,
    const ushort_t* __restrict__ d2frag, const float* __restrict__ d2b,
    const ushort_t* __restrict__ d3frag, const float* __restrict__ d3b,
    const float* __restrict__ x, const float* __restrict__ tm,
    float* __restrict__ xhat, float* __restrict__ out_idx,
    float* __restrict__ pblk)
{
  __shared__ __attribute__((aligned(16))) ushort_t s_reg1[64*264];
  __shared__ __attribute__((aligned(16))) ushort_t s_reg2[64*264];
  __shared__ int s_idx[64];
  __shared__ float s_act[64];
  __shared__ float s_rn0[64], s_rn1[64];
  __shared__ u64 s_best[64];
  __shared__ float s_im[64];
  __shared__ float s_p[4], s_w[4];

  float*    s_r  = (float*)s_reg1;        // 4096 f32 (latent input)
  ushort_t* s_al = s_reg1 + 8192;         // 8704 ush (z lo frags), ends at 16896
  ushort_t* s_ah = s_reg2;                // 8704 ush (z hi frags)
  ushort_t* s_u  = s_reg1;                // gather A1 (stride 136) / h2 (stride 264)
  ushort_t* s_h1 = s_reg2;                // h1 (stride 264)

  const int tid = threadIdx.x;
  const long m0 = (long)blockIdx.x * 64;
  const int wv = tid >> 6, lane = tid & 63;
  const int ln31 = lane & 31, half = lane >> 5;
  float blk_vqp = 0.f, blk_sim = 0.f;     // live only in tid 0

  // ---- stage: red -> s_r, imask -> s_im, init s_best ----
  {
    const int r = tid >> 2, seg = tid & 3;
    const float4* src = (const float4*)(red + (m0 + r)*64 + seg*16);
    float4* dst = (float4*)(s_r + r*64 + seg*16);
    dst[0] = src[0]; dst[1] = src[1]; dst[2] = src[2]; dst[3] = src[3];
  }
  if (tid < 64) { s_im[tid] = imask[m0 + tid]; s_best[tid] = ~0ULL; }
  __syncthreads();

  // ---- latent: z -> f16 hi/lo frags in LDS + rownorm partials (4-chain FMA) ----
  {
    const int e = tid & 127, mh = tid >> 7;
    float4 W[16];
    const float4* wp = (const float4*)(latw + (long)e*64);
    #pragma unroll
    for (int q = 0; q < 16; ++q) W[q] = wp[q];
    const float lb = latb[e];
    for (int i = 0; i < 32; ++i) {
      const int ml = mh*32 + i;                        // wave-uniform
      const float4* rp = (const float4*)(s_r + ml*64); // LDS broadcast
      float a0 = 0.f, a1 = 0.f, a2 = 0.f, a3 = 0.f;    // 4 chains: latency/4
      #pragma unroll
      for (int q = 0; q < 16; q += 4) {
        const float4 r0 = rp[q],   r1 = rp[q+1];
        const float4 r2 = rp[q+2], r3 = rp[q+3];
        a0 = fmaf(W[q].x,   r0.x, a0); a0 = fmaf(W[q].y,   r0.y, a0);
        a0 = fmaf(W[q].z,   r0.z, a0); a0 = fmaf(W[q].w,   r0.w, a0);
        a1 = fmaf(W[q+1].x, r1.x, a1); a1 = fmaf(W[q+1].y, r1.y, a1);
        a1 = fmaf(W[q+1].z, r1.z, a1); a1 = fmaf(W[q+1].w, r1.w, a1);
        a2 = fmaf(W[q+2].x, r2.x, a2); a2 = fmaf(W[q+2].y, r2.y, a2);
        a2 = fmaf(W[q+2].z, r2.z, a2); a2 = fmaf(W[q+2].w, r2.w, a2);
        a3 = fmaf(W[q+3].x, r3.x, a3); a3 = fmaf(W[q+3].y, r3.y, a3);
        a3 = fmaf(W[q+3].z, r3.z, a3); a3 = fmaf(W[q+3].w, r3.w, a3);
      }
      const float a = (a0 + a1) + (a2 + a3);
      const float z = fmaf(0.02f, a, lb) * s_im[ml];
      h2u zh, zl; zh.h = (_Float16)z; zl.h = (_Float16)(z - (float)zh.h);
      s_ah[ml*136 + e] = zh.u;
      s_al[ml*136 + e] = zl.u;
      float v = z*z;
      #pragma unroll
      for (int off = 32; off > 0; off >>= 1) v += __shfl_down(v, off);
      if (lane == 0) { if (e < 64) s_rn0[ml] = v; else s_rn1[ml] = v; }
    }
  }
  __syncthreads();

  // ---- VQ: 2 row-tiles per wave x own 128 codes; argmin -> s_best ----
  {
    const short8* ch8 = (const short8*)cbhi;
    const short8* cl8 = (const short8*)cblo;
    #pragma unroll
    for (int mtl = 0; mtl < 2; ++mtl) {
      float rnv[16];
      #pragma unroll
      for (int r = 0; r < 16; ++r) {
        const int g = mtl*32 + rowfn(r, half);
        rnv[r] = s_rn0[g] + s_rn1[g];
      }
      u64 best[16];
      #pragma unroll
      for (int r = 0; r < 16; ++r) best[r] = ~0ULL;
      for (int ct = 0; ct < 4; ++ct) {
        const int ntg = wv*4 + ct;
        half8 Bh[8], Bl[8];
        #pragma unroll
        for (int kt = 0; kt < 8; ++kt) {
          s2h a, b;
          a.s = ch8[(ntg*8 + kt)*64 + lane];
          b.s = cl8[(ntg*8 + kt)*64 + lane];
          Bh[kt] = a.h; Bl[kt] = b.h;
        }
        f32x16 acc;
        #pragma unroll
        for (int q = 0; q < 16; ++q) acc[q] = 0.f;
        const int base8 = (mtl*32 + ln31)*17 + half;
        #pragma unroll
        for (int kt = 0; kt < 8; ++kt) {
          s2h ah, al;
          ah.s = ((const short8*)s_ah)[base8 + kt*2];
          al.s = ((const short8*)s_al)[base8 + kt*2];
          acc = MFMA_F16(ah.h, Bh[kt], acc, 0, 0, 0);
          acc = MFMA_F16(ah.h, Bl[kt], acc, 0, 0, 0);
          acc = MFMA_F16(al.h, Bh[kt], acc, 0, 0, 0);
        }
        const int code = ntg*32 + ln31;
        const float nrm = cbnorm[code];
        #pragma unroll
        for (int r = 0; r < 16; ++r) {
          const float t = fmaf(-0.00390625f, acc[r], rnv[r]);  // A - p/256 (cb x512)
          const float d = t + nrm;
          const u64 pk = ((u64)__float_as_uint(d) << 32) | (u64)(unsigned)code;
          if (pk < best[r]) best[r] = pk;
        }
      }
      #pragma unroll
      for (int r = 0; r < 16; ++r)
        atomicMin(&s_best[mtl*32 + rowfn(r, half)], best[r]);
    }
  }
  __syncthreads();

  // ---- P0: indices, vq-loss, S_im partials; gather zq*im -> s_u (stride 136) ----
  if (tid < 64) {
    const u64 pk = s_best[tid];
    const int ii = (int)(unsigned)(pk & 0xffffffffULL);
    const float dd = __uint_as_float((unsigned)(pk >> 32));
    const float imv = s_im[tid];
    s_idx[tid] = ii; s_act[tid] = imv;
    out_idx[m0 + tid] = (imv > 0.f) ? (float)ii : -1.0f;
    float vqp = 1.25f * dd * (1.0f/128.0f) * imv;
    float sim = imv;
    #pragma unroll
    for (int off = 32; off > 0; off >>= 1) {
      vqp += __shfl_down(vqp, off); sim += __shfl_down(sim, off);
    }
    if (tid == 0) { blk_vqp = vqp; blk_sim = sim; }
  }
  __syncthreads();
  {
    const int row = tid >> 2, seg = tid & 3;
    const float4* src = (const float4*)(cb + (long)s_idx[row]*128 + seg*32);
    const float im = s_act[row];
    ushort_t tmp[32];
    #pragma unroll
    for (int q = 0; q < 8; ++q) {
      const float4 v = src[q];
      tmp[q*4+0] = bf16_rn(v.x*im); tmp[q*4+1] = bf16_rn(v.y*im);
      tmp[q*4+2] = bf16_rn(v.z*im); tmp[q*4+3] = bf16_rn(v.w*im);
    }
    short8* dst = (short8*)(s_u + row*136 + seg*32);
    #pragma unroll
    for (int q = 0; q < 4; ++q) dst[q] = *(short8*)&tmp[q*8];
  }
  __syncthreads();

  // ---- P1: GEMM1 (K=128): h1 = relu(zq @ d1^T + b) -> s_h1 (stride 264) ----
  {
    const short8* bf = (const short8*)d1frag;
    #pragma unroll
    for (int nti = 0; nti < 2; ++nti) {
      const int ntg = wv + nti*4;
      short8 B[8];
      #pragma unroll
      for (int kt = 0; kt < 8; ++kt) B[kt] = bf[(ntg*8 + kt)*64 + lane];
      const float bv = d1b[ntg*32 + ln31];
      #pragma unroll
      for (int mtl = 0; mtl < 2; ++mtl) {
        f32x16 acc;
        #pragma unroll
        for (int q = 0; q < 16; ++q) acc[q] = 0.f;
        const int base8 = (mtl*32 + ln31)*17 + half;
        #pragma unroll
        for (int kt = 0; kt < 8; ++kt) {
          const short8 a = ((const short8*)s_u)[base8 + kt*2];
          acc = MFMA_BF16(a, B[kt], acc, 0, 0, 0);
        }
        const int col = ntg*32 + ln31;
        #pragma unroll
        for (int r = 0; r < 16; ++r) {
          const int row = mtl*32 + rowfn(r, half);
          s_h1[row*264 + col] = bf16_rn(fmaxf(acc[r] + bv, 0.f));
        }
      }
    }
  }
  __syncthreads();

  // ---- P2: GEMM2 (K=256): h2 = relu(h1 @ d2^T + b) -> s_u (stride 264) ----
  {
    const short8* bf = (const short8*)d2frag;
    #pragma unroll
    for (int nti = 0; nti < 2; ++nti) {
      const int ntg = wv + nti*4;
      short8 B[16];
      #pragma unroll
      for (int kt = 0; kt < 16; ++kt) B[kt] = bf[(ntg*16 + kt)*64 + lane];
      const float bv = d2b[ntg*32 + ln31];
      #pragma unroll
      for (int mtl = 0; mtl < 2; ++mtl) {
        f32x16 acc;
        #pragma unroll
        for (int q = 0; q < 16; ++q) acc[q] = 0.f;
        const int base8 = (mtl*32 + ln31)*33 + half;
        #pragma unroll
        for (int kt = 0; kt < 16; ++kt) {
          const short8 a = ((const short8*)s_h1)[base8 + kt*2];
          acc = MFMA_BF16(a, B[kt], acc, 0, 0, 0);
        }
        const int col = ntg*32 + ln31;
        #pragma unroll
        for (int r = 0; r < 16; ++r) {
          const int row = mtl*32 + rowfn(r, half);
          s_u[row*264 + col] = bf16_rn(fmaxf(acc[r] + bv, 0.f));
        }
      }
    }
  }
  __syncthreads();

  // ---- P3: GEMM3 (K=256, N=100): x_hat + recon loss + S_rw -> pblk ----
  {
    const short8* bf = (const short8*)d3frag;
    const int ntg = wv;
    short8 B[16];
    #pragma unroll
    for (int kt = 0; kt < 16; ++kt) B[kt] = bf[(ntg*16 + kt)*64 + lane];
    const int col = ntg*32 + ln31;
    const float bv = (col < 100) ? d3b[col] : 0.f;
    float part = 0.f, wsum = 0.f;
    #pragma unroll
    for (int mtl = 0; mtl < 2; ++mtl) {
      f32x16 acc;
      #pragma unroll
      for (int q = 0; q < 16; ++q) acc[q] = 0.f;
      const int base8 = (mtl*32 + ln31)*33 + half;
      #pragma unroll
      for (int kt = 0; kt < 16; ++kt) {
        const short8 a = ((const short8*)s_u)[base8 + kt*2];
        acc = MFMA_BF16(a, B[kt], acc, 0, 0, 0);
      }
      if (col < 100) {
        #pragma unroll
        for (int r = 0; r < 16; ++r) {
          const long row = m0 + mtl*32 + rowfn(r, half);
          const float xh = acc[r] + bv;
          xhat[row*100 + col] = xh;
          const float wgt = imask[row] * tm[row*100 + col];
          const float df = xh - x[row*100 + col];
          part = fmaf(df*df, wgt, part);
          wsum += wgt;
        }
      }
    }
    #pragma unroll
    for (int off = 32; off > 0; off >>= 1) {
      part += __shfl_down(part, off); wsum += __shfl_down(wsum, off);
    }
    if (lane == 0) { s_p[wv] = part; s_w[wv] = wsum; }
    __syncthreads();
    if (tid == 0) {
      float* p = pblk + (long)blockIdx.x*4;
      p[0] = s_p[0]+s_p[1]+s_p[2]+s_p[3];
      p[1] = blk_vqp;
      p[2] = s_w[0]+s_w[1]+s_w[2]+s_w[3];
      p[3] = blk_sim;
    }
  }
}

// ---------------- finalize: reduce per-block partials -> scalars ----------------
__global__ __launch_bounds__(256) void finalize_kernel(
    const float* __restrict__ pblk, float* __restrict__ out)
{
  const int tid = threadIdx.x;
  const int comp = tid >> 6, lane = tid & 63;   // wave per component
  float s = 0.f;
  for (int i = lane; i < VQDEC_BLOCKS; i += 64) s += pblk[i*4 + comp];
  #pragma unroll
  for (int off = 32; off > 0; off >>= 1) s += __shfl_down(s, off);
  __shared__ float sc[4];
  if (lane == 0) sc[comp] = s;
  __syncthreads();
  if (tid == 0) {
    out[5120000] = sc[0] / fmaxf(sc[2], 1.0f);
    out[5120001] = sc[1] / fmaxf(sc[3], 1.0f);
  }
}

extern "C" void kernel_launch(void* const* d_in, const int* in_sizes, int n_in,
                              void* d_out, int out_size, void* d_ws, size_t ws_size,
                              hipStream_t stream)
{
  (void)in_sizes; (void)n_in; (void)out_size; (void)ws_size;
  const float* x     = (const float*)d_in[0];
  const float* tmsk  = (const float*)d_in[1];
  const float* imask = (const float*)d_in[2];
  const float* w1    = (const float*)d_in[3];
  const float* b1    = (const float*)d_in[4];
  const float* w2    = (const float*)d_in[5];
  const float* b2    = (const float*)d_in[6];
  const float* latw  = (const float*)d_in[7];
  const float* latb  = (const float*)d_in[8];
  const float* cb    = (const float*)d_in[9];
  const float* d1w   = (const float*)d_in[10];
  const float* d1b   = (const float*)d_in[11];
  const float* d2w   = (const float*)d_in[12];
  const float* d2b   = (const float*)d_in[13];
  const float* d3w   = (const float*)d_in[14];
  const float* d3b   = (const float*)d_in[15];
  float* out = (float*)d_out;
  float* ws  = (float*)d_ws;

  ushort_t* ebhi   = (ushort_t*)(ws + WS_ENCBHI);
  ushort_t* eblo   = (ushort_t*)(ws + WS_ENCBLO);
  ushort_t* cbhi   = (ushort_t*)(ws + WS_CBHI);
  ushort_t* cblo   = (ushort_t*)(ws + WS_CBLO);
  float*    cbnorm = ws + WS_CBNORM;
  ushort_t* d1f    = (ushort_t*)(ws + WS_D1F);
  ushort_t* d2f    = (ushort_t*)(ws + WS_D2F);
  ushort_t* d3f    = (ushort_t*)(ws + WS_D3F);
  float*    red    = ws + WS_RED;
  float*    pblk   = ws + WS_PART;
  float* xhat    = out;
  float* out_idx = out + 5120002;

  prep_kernel<<<512, 256, 0, stream>>>(w2, cb, d1w, d2w, d3w,
                                       ebhi, eblo, cbhi, cblo, d1f, d2f, d3f, cbnorm);
  encoder_kernel<<<12800, 256, 0, stream>>>(x, tmsk, imask, w1, b1, ebhi, eblo, b2, red);
  vqdec_kernel<<<VQDEC_BLOCKS, 256, 0, stream>>>(red, imask, latw, latb, cbhi, cblo,
                                                 cbnorm, cb, d1f, d1b, d2f, d2b,
                                                 d3f, d3b, x, tmsk, xhat, out_idx, pblk);
  finalize_kernel<<<1, 256, 0, stream>>>(pblk, out);
}

// Round 15
// 417.037 us; speedup vs baseline: 1.1082x; 1.0155x over previous
//
#include <hip/hip_runtime.h>
#include <stdint.h>

typedef unsigned long long u64;
typedef unsigned short ushort_t;
typedef __attribute__((ext_vector_type(8))) short short8;
typedef __attribute__((ext_vector_type(8))) _Float16 half8;
typedef __attribute__((ext_vector_type(16))) float f32x16;

// Dims: B=512,N=100 -> M=51200; T=100, L=50 conv pos, HE=64, E=128, NE=512, HD=256.
#define VQDEC_BLOCKS 800
#define ENC_BLOCKS   12800
#define PREP_BLOCKS  512

// ---------------- workspace layout (float offsets) ----------------
#define WS_ENCBHI   6656000ll    // 12288 ushort = 6144 f              -> end 6,662,144
#define WS_ENCBLO   6662144ll    // 6144 f                             -> end 6,668,288
#define WS_CBHI     6668288ll    // 65536 ushort = 32768 f             -> end 6,701,056
#define WS_CBLO     6701056ll    // 32768 f                            -> end 6,733,824
#define WS_CBNORM   6733824ll    // 512 f                              -> end 6,734,336
#define WS_D1F      6734336ll    // 32768 ushort = 16384 f             -> end 6,750,720
#define WS_D2F      6750720ll    // 65536 ushort = 32768 f             -> end 6,783,488
#define WS_D3F      6783488ll    // 32768 ushort = 16384 f             -> end 6,799,872
#define WS_RED      6902280ll    // red[51200*64] f32 = 3,276,800 f    -> end 10,179,080
#define WS_PART     10179080ll   // 800 blocks x 4 f32 partials        -> end 10,182,280

__device__ __host__ inline ushort_t bf16_rn(float v) {
  unsigned u = __float_as_uint(v);
  unsigned r = (u + 0x7fffu + ((u >> 16) & 1u)) >> 16;
  return (ushort_t)r;
}
union h2u { _Float16 h; unsigned short u; };
union s2h { short8 s; half8 h; };

// packed RNE f32x2 -> bf16x2 (v_cvt_pk_bf16_f32); low 16 bits = a, high = b.
__device__ inline unsigned pk2_bf16(float a, float b) {
  unsigned r;
  asm("v_cvt_pk_bf16_f32 %0, %1, %2" : "=v"(r) : "v"(a), "v"(b));
  return r;
}

__device__ inline int rowfn(int r, int half) { return (r & 3) + 8*(r >> 2) + 4*half; }

#define MFMA_BF16 __builtin_amdgcn_mfma_f32_32x32x16_bf16
#define MFMA_F16  __builtin_amdgcn_mfma_f32_32x32x16_f16

// ---------------- prep_enc: encoder conv2 B-frags only (48 blocks, ~3us) ----------------
__global__ __launch_bounds__(256) void prep_enc_kernel(
    const float* __restrict__ w2,
    ushort_t* __restrict__ ebhi, ushort_t* __restrict__ eblo)
{
  const int idx = blockIdx.x*256 + threadIdx.x;   // grid = 48*256 = 12288 exactly
  int j = idx & 7, l6 = (idx >> 3) & 63, f = idx >> 9;
  int kt = f & 3, ntt = (f >> 2) & 1, t = f >> 3;
  int oc = ntt*32 + (l6 & 31);
  int ic = kt*16 + (l6 >> 5)*8 + j;
  float v = w2[(oc*64 + ic)*3 + t];
  ushort_t hi = bf16_rn(v);
  float hf = __uint_as_float(((unsigned)hi) << 16);
  ebhi[idx] = hi; eblo[idx] = bf16_rn(v - hf);
}

// prep-rest body: cb/d1/d2/d3 frags + cbnorm (197,120 items), run by encoder tail blocks
__device__ void prep_rest(int pb, int tid,
    const float* __restrict__ cb,
    const float* __restrict__ d1w, const float* __restrict__ d2w,
    const float* __restrict__ d3w,
    ushort_t* __restrict__ cbhi, ushort_t* __restrict__ cblo,
    ushort_t* __restrict__ d1f, ushort_t* __restrict__ d2f,
    ushort_t* __restrict__ d3f, float* __restrict__ cbnorm)
{
  const int total = 65536 + 32768 + 65536 + 32768 + 512;
  for (int i = pb*256 + tid; i < total; i += PREP_BLOCKS*256) {
    int idx = i;
    if (idx < 65536) {
      // codebook f16 hi/lo frags, scaled x512: ntg16 x kt8
      int j = idx & 7, l6 = (idx >> 3) & 63, f = idx >> 9;
      int kt = f & 7, ntg = f >> 3;
      int k = kt*16 + (l6 >> 5)*8 + j;
      int n = ntg*32 + (l6 & 31);
      float v = cb[n*128 + k] * 512.0f;
      h2u a, b; a.h = (_Float16)v;
      b.h = (_Float16)(v - (float)a.h);
      cbhi[idx] = a.u; cblo[idx] = b.u; continue;
    }
    idx -= 65536;
    if (idx < 32768) {
      int j = idx & 7, l6 = (idx >> 3) & 63, f = idx >> 9;
      int kt = f & 7, ntg = f >> 3;
      int k = kt*16 + (l6 >> 5)*8 + j;
      int n = ntg*32 + (l6 & 31);
      d1f[idx] = bf16_rn(d1w[n*128 + k]); continue;
    }
    idx -= 32768;
    if (idx < 65536) {
      int j = idx & 7, l6 = (idx >> 3) & 63, f = idx >> 9;
      int kt = f & 15, ntg = f >> 4;
      int k = kt*16 + (l6 >> 5)*8 + j;
      int n = ntg*32 + (l6 & 31);
      d2f[idx] = bf16_rn(d2w[n*256 + k]); continue;
    }
    idx -= 65536;
    if (idx < 32768) {
      int j = idx & 7, l6 = (idx >> 3) & 63, f = idx >> 9;
      int kt = f & 15, ntg = f >> 4;
      int k = kt*16 + (l6 >> 5)*8 + j;
      int n = ntg*32 + (l6 & 31);
      d3f[idx] = (n < 100) ? bf16_rn(d3w[n*256 + k]) : (ushort_t)0; continue;
    }
    idx -= 32768;
    { double s = 0.0; const float* c = cb + idx*128;
      for (int e = 0; e < 128; ++e) { double v = (double)c[e]; s += v*v; }
      cbnorm[idx] = (float)s; }
  }
}

// ---------------- encoder v6 + prep-rest tail blocks ----------------
// Blocks [0,12800): one wave per m, zero barriers, 3 blocks/CU (unchanged R14 body).
// Blocks [12800,13312): pack cb/dec frags + cbnorm (hidden in encoder drain).
__global__ __launch_bounds__(256, 3) void encoder_kernel(
    const float* __restrict__ x, const float* __restrict__ tm,
    const float* __restrict__ imask,
    const float* w1, const float* b1,
    const ushort_t* __restrict__ ebhi, const ushort_t* __restrict__ eblo,
    const float* b2, float* __restrict__ red,
    const float* __restrict__ cb,
    const float* __restrict__ d1w, const float* __restrict__ d2w,
    const float* __restrict__ d3w,
    ushort_t* __restrict__ cbhi, ushort_t* __restrict__ cblo,
    ushort_t* __restrict__ d1f, ushort_t* __restrict__ d2f,
    ushort_t* __restrict__ d3f, float* __restrict__ cbnorm)
{
  __shared__ ushort_t s_H[4][52*128];   // 53,248 B total
  const int tid  = threadIdx.x;
  if (blockIdx.x >= ENC_BLOCKS) {       // block-uniform branch; no barriers in kernel
    prep_rest((int)blockIdx.x - ENC_BLOCKS, tid, cb, d1w, d2w, d3w,
              cbhi, cblo, d1f, d2f, d3f, cbnorm);
    return;
  }
  const int wv   = __builtin_amdgcn_readfirstlane((int)(tid >> 6));
  const int lane = tid & 63;
  const int ln31 = lane & 31, half = lane >> 5;
  const long m   = (long)blockIdx.x*4 + wv;     // wave-uniform
  const float imv = imask[m];                   // scalar load
  ushort_t* Hw  = s_H[wv];

  // ---- conv1: inputs straight from global (3 float2 pairs per lane) ----
  {
    const int p = (lane < 50) ? lane : 0;
    const long xb = m*100 + 2*p;
    const float2 x0v = *(const float2*)(x + xb);
    const float2 t0v = *(const float2*)(tm + xb);
    float2 xmv = {0.f, 0.f}, tmv = {0.f, 0.f};
    float2 xpv = {0.f, 0.f}, tpv = {0.f, 0.f};
    if (p > 0)  { xmv = *(const float2*)(x + xb - 2); tmv = *(const float2*)(tm + xb - 2); }
    if (p < 49) { xpv = *(const float2*)(x + xb + 2); tpv = *(const float2*)(tm + xb + 2); }
    const float a0 = xmv.x*tmv.x, c0 = xmv.y*tmv.y;
    const float a1 = x0v.x*t0v.x, c1 = x0v.y*t0v.y;
    const float a2 = xpv.x*tpv.x, c2 = xpv.y*tpv.y;
    const int row = lane + 1;                    // H row = pos+1
    const int sw  = ((row & 7) << 4) | (((row >> 3) & 1) << 7);  // 16-slot swizzle
    char* rbase = (char*)(Hw + row*128);
    #pragma unroll
    for (int g = 0; g < 4; ++g) {
      unsigned hi8[8], lo8[8];
      #pragma unroll
      for (int pr = 0; pr < 8; ++pr) {
        const int o = g*16 + pr*2;
        const float* wA = w1 + (long)o*6;       // wave-uniform -> s_load
        const float* wB = wA + 6;
        float sA = 0.f, sB = 0.f;
        sA = fmaf(wA[0], a0, sA); sA = fmaf(wA[1], a1, sA); sA = fmaf(wA[2], a2, sA);
        sA = fmaf(wA[3], c0, sA); sA = fmaf(wA[4], c1, sA); sA = fmaf(wA[5], c2, sA);
        sB = fmaf(wB[0], a0, sB); sB = fmaf(wB[1], a1, sB); sB = fmaf(wB[2], a2, sB);
        sB = fmaf(wB[3], c0, sB); sB = fmaf(wB[4], c1, sB); sB = fmaf(wB[5], c2, sB);
        const float hA = fmaxf(fmaf(imv, sA, b1[o]),     0.f);
        const float hB = fmaxf(fmaf(imv, sB, b1[o + 1]), 0.f);
        const unsigned h = pk2_bf16(hA, hB);
        const float ha = __uint_as_float(h << 16);
        const float hb = __uint_as_float(h & 0xffff0000u);
        lo8[pr] = pk2_bf16(hA - ha, hB - hb);
        hi8[pr] = h;
      }
      if (lane < 50) {
        *(short8*)(rbase + ((g*32)        ^ sw)) = *(short8*)&hi8[0];
        *(short8*)(rbase + ((g*32 + 16)   ^ sw)) = *(short8*)&hi8[4];
        *(short8*)(rbase + ((g*32 + 128)  ^ sw)) = *(short8*)&lo8[0];
        *(short8*)(rbase + ((g*32 + 144)  ^ sw)) = *(short8*)&lo8[4];
      }
    }
    if (lane == 50 || lane == 51) {          // zero halo rows 0 and 51 (swizzle-invariant)
      const int zr = (lane == 50) ? 0 : 51;
      short8 z8 = {};
      short8* d = (short8*)(Hw + zr*128);
      #pragma unroll
      for (int i = 0; i < 16; ++i) d[i] = z8;
    }
  }
  // intra-wave LDS write->read fence (wave-private slice; no barrier)
  asm volatile("s_waitcnt lgkmcnt(0)" ::: "memory");
  __builtin_amdgcn_sched_barrier(0);

  // ---- conv2 MFMA: all 4 (mt,nt) tiles of this wave's m ----
  f32x16 acc00, acc01, acc10, acc11;
  #pragma unroll
  for (int q = 0; q < 16; ++q) { acc00[q] = 0.f; acc01[q] = 0.f; acc10[q] = 0.f; acc11[q] = 0.f; }
  {
    const short8* bh8 = (const short8*)ebhi;
    const short8* bl8 = (const short8*)eblo;
    for (int t = 0; t < 3; ++t) {
      const int r0 = ln31 + t;                // 0..33, valid
      int r1 = 32 + ln31 + t;                 // 32..65 -> clamp to zero halo 51
      if (r1 > 51) r1 = 51;
      const int sw0 = ((r0 & 7) << 4) | (((r0 >> 3) & 1) << 7);
      const int sw1 = ((r1 & 7) << 4) | (((r1 >> 3) & 1) << 7);
      const char* b0p = (const char*)(Hw + r0*128);
      const char* b1p = (const char*)(Hw + r1*128);
      #pragma unroll
      for (int kt = 0; kt < 4; ++kt) {
        const int f0 = (t*2 + 0)*4 + kt;
        const int f1 = (t*2 + 1)*4 + kt;
        const int offh = kt*32 + half*16;
        const short8 Bh0 = bh8[f0*64 + lane], Bl0 = bl8[f0*64 + lane];
        const short8 Bh1 = bh8[f1*64 + lane], Bl1 = bl8[f1*64 + lane];
        const short8 ah0 = *(const short8*)(b0p + (offh ^ sw0));
        const short8 al0 = *(const short8*)(b0p + ((offh + 128) ^ sw0));
        const short8 ah1 = *(const short8*)(b1p + (offh ^ sw1));
        const short8 al1 = *(const short8*)(b1p + ((offh + 128) ^ sw1));
        acc00 = MFMA_BF16(ah0, Bh0, acc00, 0, 0, 0);
        acc00 = MFMA_BF16(ah0, Bl0, acc00, 0, 0, 0);
        acc00 = MFMA_BF16(al0, Bh0, acc00, 0, 0, 0);
        acc01 = MFMA_BF16(ah0, Bh1, acc01, 0, 0, 0);
        acc01 = MFMA_BF16(ah0, Bl1, acc01, 0, 0, 0);
        acc01 = MFMA_BF16(al0, Bh1, acc01, 0, 0, 0);
        acc10 = MFMA_BF16(ah1, Bh0, acc10, 0, 0, 0);
        acc10 = MFMA_BF16(ah1, Bl0, acc10, 0, 0, 0);
        acc10 = MFMA_BF16(al1, Bh0, acc10, 0, 0, 0);
        acc11 = MFMA_BF16(ah1, Bh1, acc11, 0, 0, 0);
        acc11 = MFMA_BF16(ah1, Bl1, acc11, 0, 0, 0);
        acc11 = MFMA_BF16(al1, Bh1, acc11, 0, 0, 0);
      }
    }
  }

  // ---- relu + bias + masked position-sum -> red[m][64] (f32, global) ----
  {
    const float bv0 = b2[ln31];
    const float bv1 = b2[32 + ln31];
    float s0 = 0.f, s1 = 0.f;
    #pragma unroll
    for (int r = 0; r < 16; ++r) {
      s0 += fmaxf(acc00[r] + bv0, 0.f);              // mt=0: pos 0..31 all valid
      s1 += fmaxf(acc01[r] + bv1, 0.f);
      const int mpos = 32 + rowfn(r, half);          // mt=1: keep pos<50
      const float v10 = fmaxf(acc10[r] + bv0, 0.f);
      const float v11 = fmaxf(acc11[r] + bv1, 0.f);
      if (mpos < 50) { s0 += v10; s1 += v11; }
    }
    s0 += __shfl_xor(s0, 32);
    s1 += __shfl_xor(s1, 32);
    if (half == 0) {
      red[m*64 + ln31]      = s0;
      red[m*64 + 32 + ln31] = s1;
    }
  }
}

// ---------------- fused latent -> VQ -> decoder (64 m per block, R14 champion) ----------------
__global__ __launch_bounds__(256, 2) void vqdec_kernel(
    const float* __restrict__ red, const float* __restrict__ imask,
    const float* __restrict__ latw, const float* __restrict__ latb,
    const ushort_t* __restrict__ cbhi, const ushort_t* __restrict__ cblo,
    const float* __restrict__ cbnorm, const float* __restrict__ cb,
    const ushort_t* __restrict__ d1frag, const float* __restrict__ d1b,
    const ushort_t* __restrict__ d2frag, const float* __restrict__ d2b,
    const ushort_t* __restrict__ d3frag, const float* __restrict__ d3b,
    const float* __restrict__ x, const float* __restrict__ tm,
    float* __restrict__ xhat, float* __restrict__ out_idx,
    float* __restrict__ pblk)
{
  __shared__ __attribute__((aligned(16))) ushort_t s_reg1[64*264];
  __shared__ __attribute__((aligned(16))) ushort_t s_reg2[64*264];
  __shared__ int s_idx[64];
  __shared__ float s_act[64];
  __shared__ float s_rn0[64], s_rn1[64];
  __shared__ u64 s_best[64];
  __shared__ float s_im[64];
  __shared__ float s_p[4], s_w[4];

  float*    s_r  = (float*)s_reg1;        // 4096 f32 (latent input)
  ushort_t* s_al = s_reg1 + 8192;         // 8704 ush (z lo frags), ends at 16896
  ushort_t* s_ah = s_reg2;                // 8704 ush (z hi frags)
  ushort_t* s_u  = s_reg1;                // gather A1 (stride 136) / h2 (stride 264)
  ushort_t* s_h1 = s_reg2;                // h1 (stride 264)

  const int tid = threadIdx.x;
  const long m0 = (long)blockIdx.x * 64;
  const int wv = tid >> 6, lane = tid & 63;
  const int ln31 = lane & 31, half = lane >> 5;
  float blk_vqp = 0.f, blk_sim = 0.f;     // live only in tid 0

  // ---- stage: red -> s_r, imask -> s_im, init s_best ----
  {
    const int r = tid >> 2, seg = tid & 3;
    const float4* src = (const float4*)(red + (m0 + r)*64 + seg*16);
    float4* dst = (float4*)(s_r + r*64 + seg*16);
    dst[0] = src[0]; dst[1] = src[1]; dst[2] = src[2]; dst[3] = src[3];
  }
  if (tid < 64) { s_im[tid] = imask[m0 + tid]; s_best[tid] = ~0ULL; }
  __syncthreads();

  // ---- latent: z -> f16 hi/lo frags in LDS + rownorm partials (4-chain FMA) ----
  {
    const int e = tid & 127, mh = tid >> 7;
    float4 W[16];
    const float4* wp = (const float4*)(latw + (long)e*64);
    #pragma unroll
    for (int q = 0; q < 16; ++q) W[q] = wp[q];
    const float lb = latb[e];
    for (int i = 0; i < 32; ++i) {
      const int ml = mh*32 + i;                        // wave-uniform
      const float4* rp = (const float4*)(s_r + ml*64); // LDS broadcast
      float a0 = 0.f, a1 = 0.f, a2 = 0.f, a3 = 0.f;    // 4 chains: latency/4
      #pragma unroll
      for (int q = 0; q < 16; q += 4) {
        const float4 r0 = rp[q],   r1 = rp[q+1];
        const float4 r2 = rp[q+2], r3 = rp[q+3];
        a0 = fmaf(W[q].x,   r0.x, a0); a0 = fmaf(W[q].y,   r0.y, a0);
        a0 = fmaf(W[q].z,   r0.z, a0); a0 = fmaf(W[q].w,   r0.w, a0);
        a1 = fmaf(W[q+1].x, r1.x, a1); a1 = fmaf(W[q+1].y, r1.y, a1);
        a1 = fmaf(W[q+1].z, r1.z, a1); a1 = fmaf(W[q+1].w, r1.w, a1);
        a2 = fmaf(W[q+2].x, r2.x, a2); a2 = fmaf(W[q+2].y, r2.y, a2);
        a2 = fmaf(W[q+2].z, r2.z, a2); a2 = fmaf(W[q+2].w, r2.w, a2);
        a3 = fmaf(W[q+3].x, r3.x, a3); a3 = fmaf(W[q+3].y, r3.y, a3);
        a3 = fmaf(W[q+3].z, r3.z, a3); a3 = fmaf(W[q+3].w, r3.w, a3);
      }
      const float a = (a0 + a1) + (a2 + a3);
      const float z = fmaf(0.02f, a, lb) * s_im[ml];
      h2u zh, zl; zh.h = (_Float16)z; zl.h = (_Float16)(z - (float)zh.h);
      s_ah[ml*136 + e] = zh.u;
      s_al[ml*136 + e] = zl.u;
      float v = z*z;
      #pragma unroll
      for (int off = 32; off > 0; off >>= 1) v += __shfl_down(v, off);
      if (lane == 0) { if (e < 64) s_rn0[ml] = v; else s_rn1[ml] = v; }
    }
  }
  __syncthreads();

  // ---- VQ: 2 row-tiles per wave x own 128 codes; argmin -> s_best ----
  {
    const short8* ch8 = (const short8*)cbhi;
    const short8* cl8 = (const short8*)cblo;
    #pragma unroll
    for (int mtl = 0; mtl < 2; ++mtl) {
      float rnv[16];
      #pragma unroll
      for (int r = 0; r < 16; ++r) {
        const int g = mtl*32 + rowfn(r, half);
        rnv[r] = s_rn0[g] + s_rn1[g];
      }
      u64 best[16];
      #pragma unroll
      for (int r = 0; r < 16; ++r) best[r] = ~0ULL;
      for (int ct = 0; ct < 4; ++ct) {
        const int ntg = wv*4 + ct;
        half8 Bh[8], Bl[8];
        #pragma unroll
        for (int kt = 0; kt < 8; ++kt) {
          s2h a, b;
          a.s = ch8[(ntg*8 + kt)*64 + lane];
          b.s = cl8[(ntg*8 + kt)*64 + lane];
          Bh[kt] = a.h; Bl[kt] = b.h;
        }
        f32x16 acc;
        #pragma unroll
        for (int q = 0; q < 16; ++q) acc[q] = 0.f;
        const int base8 = (mtl*32 + ln31)*17 + half;
        #pragma unroll
        for (int kt = 0; kt < 8; ++kt) {
          s2h ah, al;
          ah.s = ((const short8*)s_ah)[base8 + kt*2];
          al.s = ((const short8*)s_al)[base8 + kt*2];
          acc = MFMA_F16(ah.h, Bh[kt], acc, 0, 0, 0);
          acc = MFMA_F16(ah.h, Bl[kt], acc, 0, 0, 0);
          acc = MFMA_F16(al.h, Bh[kt], acc, 0, 0, 0);
        }
        const int code = ntg*32 + ln31;
        const float nrm = cbnorm[code];
        #pragma unroll
        for (int r = 0; r < 16; ++r) {
          const float t = fmaf(-0.00390625f, acc[r], rnv[r]);  // A - p/256 (cb x512)
          const float d = t + nrm;
          const u64 pk = ((u64)__float_as_uint(d) << 32) | (u64)(unsigned)code;
          if (pk < best[r]) best[r] = pk;
        }
      }
      #pragma unroll
      for (int r = 0; r < 16; ++r)
        atomicMin(&s_best[mtl*32 + rowfn(r, half)], best[r]);
    }
  }
  __syncthreads();

  // ---- P0: indices, vq-loss, S_im partials; gather zq*im -> s_u (stride 136) ----
  if (tid < 64) {
    const u64 pk = s_best[tid];
    const int ii = (int)(unsigned)(pk & 0xffffffffULL);
    const float dd = __uint_as_float((unsigned)(pk >> 32));
    const float imv = s_im[tid];
    s_idx[tid] = ii; s_act[tid] = imv;
    out_idx[m0 + tid] = (imv > 0.f) ? (float)ii : -1.0f;
    float vqp = 1.25f * dd * (1.0f/128.0f) * imv;
    float sim = imv;
    #pragma unroll
    for (int off = 32; off > 0; off >>= 1) {
      vqp += __shfl_down(vqp, off); sim += __shfl_down(sim, off);
    }
    if (tid == 0) { blk_vqp = vqp; blk_sim = sim; }
  }
  __syncthreads();
  {
    const int row = tid >> 2, seg = tid & 3;
    const float4* src = (const float4*)(cb + (long)s_idx[row]*128 + seg*32);
    const float im = s_act[row];
    ushort_t tmp[32];
    #pragma unroll
    for (int q = 0; q < 8; ++q) {
      const float4 v = src[q];
      tmp[q*4+0] = bf16_rn(v.x*im); tmp[q*4+1] = bf16_rn(v.y*im);
      tmp[q*4+2] = bf16_rn(v.z*im); tmp[q*4+3] = bf16_rn(v.w*im);
    }
    short8* dst = (short8*)(s_u + row*136 + seg*32);
    #pragma unroll
    for (int q = 0; q < 4; ++q) dst[q] = *(short8*)&tmp[q*8];
  }
  __syncthreads();

  // ---- P1: GEMM1 (K=128): h1 = relu(zq @ d1^T + b) -> s_h1 (stride 264) ----
  {
    const short8* bf = (const short8*)d1frag;
    #pragma unroll
    for (int nti = 0; nti < 2; ++nti) {
      const int ntg = wv + nti*4;
      short8 B[8];
      #pragma unroll
      for (int kt = 0; kt < 8; ++kt) B[kt] = bf[(ntg*8 + kt)*64 + lane];
      const float bv = d1b[ntg*32 + ln31];
      #pragma unroll
      for (int mtl = 0; mtl < 2; ++mtl) {
        f32x16 acc;
        #pragma unroll
        for (int q = 0; q < 16; ++q) acc[q] = 0.f;
        const int base8 = (mtl*32 + ln31)*17 + half;
        #pragma unroll
        for (int kt = 0; kt < 8; ++kt) {
          const short8 a = ((const short8*)s_u)[base8 + kt*2];
          acc = MFMA_BF16(a, B[kt], acc, 0, 0, 0);
        }
        const int col = ntg*32 + ln31;
        #pragma unroll
        for (int r = 0; r < 16; ++r) {
          const int row = mtl*32 + rowfn(r, half);
          s_h1[row*264 + col] = bf16_rn(fmaxf(acc[r] + bv, 0.f));
        }
      }
    }
  }
  __syncthreads();

  // ---- P2: GEMM2 (K=256): h2 = relu(h1 @ d2^T + b) -> s_u (stride 264) ----
  {
    const short8* bf = (const short8*)d2frag;
    #pragma unroll
    for (int nti = 0; nti < 2; ++nti) {
      const int ntg = wv + nti*4;
      short8 B[16];
      #pragma unroll
      for (int kt = 0; kt < 16; ++kt) B[kt] = bf[(ntg*16 + kt)*64 + lane];
      const float bv = d2b[ntg*32 + ln31];
      #pragma unroll
      for (int mtl = 0; mtl < 2; ++mtl) {
        f32x16 acc;
        #pragma unroll
        for (int q = 0; q < 16; ++q) acc[q] = 0.f;
        const int base8 = (mtl*32 + ln31)*33 + half;
        #pragma unroll
        for (int kt = 0; kt < 16; ++kt) {
          const short8 a = ((const short8*)s_h1)[base8 + kt*2];
          acc = MFMA_BF16(a, B[kt], acc, 0, 0, 0);
        }
        const int col = ntg*32 + ln31;
        #pragma unroll
        for (int r = 0; r < 16; ++r) {
          const int row = mtl*32 + rowfn(r, half);
          s_u[row*264 + col] = bf16_rn(fmaxf(acc[r] + bv, 0.f));
        }
      }
    }
  }
  __syncthreads();

  // ---- P3: GEMM3 (K=256, N=100): x_hat + recon loss + S_rw -> pblk ----
  {
    const short8* bf = (const short8*)d3frag;
    const int ntg = wv;
    short8 B[16];
    #pragma unroll
    for (int kt = 0; kt < 16; ++kt) B[kt] = bf[(ntg*16 + kt)*64 + lane];
    const int col = ntg*32 + ln31;
    const float bv = (col < 100) ? d3b[col] : 0.f;
    float part = 0.f, wsum = 0.f;
    #pragma unroll
    for (int mtl = 0; mtl < 2; ++mtl) {
      f32x16 acc;
      #pragma unroll
      for (int q = 0; q < 16; ++q) acc[q] = 0.f;
      const int base8 = (mtl*32 + ln31)*33 + half;
      #pragma unroll
      for (int kt = 0; kt < 16; ++kt) {
        const short8 a = ((const short8*)s_u)[base8 + kt*2];
        acc = MFMA_BF16(a, B[kt], acc, 0, 0, 0);
      }
      if (col < 100) {
        #pragma unroll
        for (int r = 0; r < 16; ++r) {
          const long row = m0 + mtl*32 + rowfn(r, half);
          const float xh = acc[r] + bv;
          xhat[row*100 + col] = xh;
          const float wgt = imask[row] * tm[row*100 + col];
          const float df = xh - x[row*100 + col];
          part = fmaf(df*df, wgt, part);
          wsum += wgt;
        }
      }
    }
    #pragma unroll
    for (int off = 32; off > 0; off >>= 1) {
      part += __shfl_down(part, off); wsum += __shfl_down(wsum, off);
    }
    if (lane == 0) { s_p[wv] = part; s_w[wv] = wsum; }
    __syncthreads();
    if (tid == 0) {
      float* p = pblk + (long)blockIdx.x*4;
      p[0] = s_p[0]+s_p[1]+s_p[2]+s_p[3];
      p[1] = blk_vqp;
      p[2] = s_w[0]+s_w[1]+s_w[2]+s_w[3];
      p[3] = blk_sim;
    }
  }
}

// ---------------- finalize: reduce per-block partials -> scalars ----------------
__global__ __launch_bounds__(256) void finalize_kernel(
    const float* __restrict__ pblk, float* __restrict__ out)
{
  const int tid = threadIdx.x;
  const int comp = tid >> 6, lane = tid & 63;   // wave per component
  float s = 0.f;
  for (int i = lane; i < VQDEC_BLOCKS; i += 64) s += pblk[i*4 + comp];
  #pragma unroll
  for (int off = 32; off > 0; off >>= 1) s += __shfl_down(s, off);
  __shared__ float sc[4];
  if (lane == 0) sc[comp] = s;
  __syncthreads();
  if (tid == 0) {
    out[5120000] = sc[0] / fmaxf(sc[2], 1.0f);
    out[5120001] = sc[1] / fmaxf(sc[3], 1.0f);
  }
}

extern "C" void kernel_launch(void* const* d_in, const int* in_sizes, int n_in,
                              void* d_out, int out_size, void* d_ws, size_t ws_size,
                              hipStream_t stream)
{
  (void)in_sizes; (void)n_in; (void)out_size; (void)ws_size;
  const float* x     = (const float*)d_in[0];
  const float* tmsk  = (const float*)d_in[1];
  const float* imask = (const float*)d_in[2];
  const float* w1    = (const float*)d_in[3];
  const float* b1    = (const float*)d_in[4];
  const float* w2    = (const float*)d_in[5];
  const float* b2    = (const float*)d_in[6];
  const float* latw  = (const float*)d_in[7];
  const float* latb  = (const float*)d_in[8];
  const float* cb    = (const float*)d_in[9];
  const float* d1w   = (const float*)d_in[10];
  const float* d1b   = (const float*)d_in[11];
  const float* d2w   = (const float*)d_in[12];
  const float* d2b   = (const float*)d_in[13];
  const float* d3w   = (const float*)d_in[14];
  const float* d3b   = (const float*)d_in[15];
  float* out = (float*)d_out;
  float* ws  = (float*)d_ws;

  ushort_t* ebhi   = (ushort_t*)(ws + WS_ENCBHI);
  ushort_t* eblo   = (ushort_t*)(ws + WS_ENCBLO);
  ushort_t* cbhi   = (ushort_t*)(ws + WS_CBHI);
  ushort_t* cblo   = (ushort_t*)(ws + WS_CBLO);
  float*    cbnorm = ws + WS_CBNORM;
  ushort_t* d1f    = (ushort_t*)(ws + WS_D1F);
  ushort_t* d2f    = (ushort_t*)(ws + WS_D2F);
  ushort_t* d3f    = (ushort_t*)(ws + WS_D3F);
  float*    red    = ws + WS_RED;
  float*    pblk   = ws + WS_PART;
  float* xhat    = out;
  float* out_idx = out + 5120002;

  prep_enc_kernel<<<48, 256, 0, stream>>>(w2, ebhi, eblo);
  encoder_kernel<<<ENC_BLOCKS + PREP_BLOCKS, 256, 0, stream>>>(
      x, tmsk, imask, w1, b1, ebhi, eblo, b2, red,
      cb, d1w, d2w, d3w, cbhi, cblo, d1f, d2f, d3f, cbnorm);
  vqdec_kernel<<<VQDEC_BLOCKS, 256, 0, stream>>>(red, imask, latw, latb, cbhi, cblo,
                                                 cbnorm, cb, d1f, d1b, d2f, d2b,
                                                 d3f, d3b, x, tmsk, xhat, out_idx, pblk);
  finalize_kernel<<<1, 256, 0, stream>>>(pblk, out);
}